// Round 6
// baseline (895.351 us; speedup 1.0000x reference)
//
#include <hip/hip_runtime.h>

typedef unsigned short u16;
typedef unsigned int u32;
typedef short v8s __attribute__((ext_vector_type(8)));
typedef float f32x4 __attribute__((ext_vector_type(4)));
typedef float f32x16 __attribute__((ext_vector_type(16)));

#define S_LEN 4096
#define DM 1024
#define HDIM 64
#define CEXP 0.18033688f /* 0.125 * log2(e), folded into Q at GEMM epilogue */

// ---- helpers ----------------------------------------------------------
__device__ __forceinline__ u16 f2bs(float f) {
  u32 u = __float_as_uint(f);
  u32 r = 0x7FFFu + ((u >> 16) & 1u);
  return (u16)((u + r) >> 16);
}

__device__ __forceinline__ float fexp2(float x) {
  float r;
  asm("v_exp_f32 %0, %1" : "=v"(r) : "v"(x));   // raw 2^x, args bounded
  return r;
}

__device__ __forceinline__ void gstage16(const void* g, void* lds_wave_base) {
  __builtin_amdgcn_global_load_lds(
      (const __attribute__((address_space(1))) u32*)g,
      (__attribute__((address_space(3))) u32*)lds_wave_base, 16, 0, 0);
}

__device__ __forceinline__ f32x16 vzero16() {
  f32x16 v;
#pragma unroll
  for (int r = 0; r < 16; ++r) v[r] = 0.f;
  return v;
}

// ---- elementwise fp32 -> bf16 -----------------------------------------
__global__ void k_cvt(const float* __restrict__ in, u16* __restrict__ out) {
  const int i = blockIdx.x * blockDim.x + threadIdx.x;
  const float4* p = reinterpret_cast<const float4*>(in) + (size_t)i * 2;
  float4 a = p[0], b = p[1];
  u16 t[8] = {f2bs(a.x), f2bs(a.y), f2bs(a.z), f2bs(a.w),
              f2bs(b.x), f2bs(b.y), f2bs(b.z), f2bs(b.w)};
  reinterpret_cast<uint4*>(out)[i] = *reinterpret_cast<const uint4*>(t);
}

// ---- weight transpose+convert: w[K][N] fp32 -> wt[N][K] bf16 ----------
__global__ __launch_bounds__(256) void k_wtrans(
    const float* __restrict__ w0, const float* __restrict__ w1,
    const float* __restrict__ w2, const float* __restrict__ w3,
    u16* __restrict__ t0, u16* __restrict__ t1,
    u16* __restrict__ t2, u16* __restrict__ t3) {
  __shared__ float tile[32][33];
  const float* w; u16* wt;
  switch (blockIdx.z) {
    case 0: w = w0; wt = t0; break;
    case 1: w = w1; wt = t1; break;
    case 2: w = w2; wt = t2; break;
    default: w = w3; wt = t3; break;
  }
  const int r = threadIdx.x >> 3;
  const int c4 = (threadIdx.x & 7) * 4;
  const int k0 = blockIdx.x * 32, n0 = blockIdx.y * 32;
  float4 v = *reinterpret_cast<const float4*>(w + (size_t)(k0 + r) * DM + n0 + c4);
  tile[r][c4] = v.x; tile[r][c4 + 1] = v.y; tile[r][c4 + 2] = v.z; tile[r][c4 + 3] = v.w;
  __syncthreads();
  u16 o4[4] = {f2bs(tile[c4][r]), f2bs(tile[c4 + 1][r]),
               f2bs(tile[c4 + 2][r]), f2bs(tile[c4 + 3][r])};
  *reinterpret_cast<uint2*>(wt + (size_t)(n0 + r) * DM + k0 + c4) =
      *reinterpret_cast<const uint2*>(o4);
}

// ---- GEMM core: C[M=4096,N=1024] = A[bf16, M,K] @ Bt[bf16, N,K]^T + bias
template <int MODE>
__device__ __forceinline__ void gemm_core(
    u16* __restrict__ As, u16* __restrict__ Bs,
    const u16* __restrict__ A, const u16* __restrict__ Bt,
    const float* __restrict__ bias, void* __restrict__ Cout, float oscale) {
  constexpr int K = DM, N = DM;
  const int tid = threadIdx.x;
  const int lane = tid & 63, wave = tid >> 6;
  const int wm = wave >> 1, wn = wave & 1;
  const int l15 = lane & 15, l4 = lane >> 4;
  const int bm0 = blockIdx.x * 128, bn0 = blockIdx.y * 128;

  f32x4 acc[4][4];
#pragma unroll
  for (int m = 0; m < 4; ++m)
#pragma unroll
    for (int n = 0; n < 4; ++n) acc[m][n] = 0.f;

  const int s0 = tid, s1 = tid + 256;
  const int ra0 = s0 >> 2, ca0 = ((s0 & 3) ^ ((ra0 >> 1) & 3)) * 8;
  const int ra1 = s1 >> 2, ca1 = ((s1 & 3) ^ ((ra1 >> 1) & 3)) * 8;
  const u16* Ab = A + (size_t)bm0 * K;
  const u16* Bb = Bt + (size_t)bn0 * K;
  u16* ldsA0 = As + (size_t)(wave * 64) * 8;
  u16* ldsA1 = As + (size_t)(256 + wave * 64) * 8;
  u16* ldsB0 = Bs + (size_t)(wave * 64) * 8;
  u16* ldsB1 = Bs + (size_t)(256 + wave * 64) * 8;

  for (int k0 = 0; k0 < K; k0 += 32) {
    gstage16(Ab + (size_t)ra0 * K + k0 + ca0, ldsA0);
    gstage16(Ab + (size_t)ra1 * K + k0 + ca1, ldsA1);
    gstage16(Bb + (size_t)ra0 * K + k0 + ca0, ldsB0);
    gstage16(Bb + (size_t)ra1 * K + k0 + ca1, ldsB1);
    __syncthreads();
    v8s af[4], bfr[4];
#pragma unroll
    for (int m = 0; m < 4; ++m) {
      const int rowa = wm * 64 + m * 16 + l15;
      af[m] = *reinterpret_cast<const v8s*>(
          As + (size_t)(rowa * 4 + (l4 ^ ((rowa >> 1) & 3))) * 8);
      const int rowb = wn * 64 + m * 16 + l15;
      bfr[m] = *reinterpret_cast<const v8s*>(
          Bs + (size_t)(rowb * 4 + (l4 ^ ((rowb >> 1) & 3))) * 8);
    }
#pragma unroll
    for (int m = 0; m < 4; ++m)
#pragma unroll
      for (int n = 0; n < 4; ++n)
        acc[m][n] = __builtin_amdgcn_mfma_f32_16x16x32_bf16(af[m], bfr[n], acc[m][n], 0, 0, 0);
    __syncthreads();
  }

#pragma unroll
  for (int m = 0; m < 4; ++m) {
    const int gs0 = bm0 + wm * 64 + m * 16 + l4 * 4;
#pragma unroll
    for (int n = 0; n < 4; ++n) {
      const int gn = bn0 + wn * 64 + n * 16 + l15;
      const float bv = bias[gn];
      if (MODE == 0) {
        u16* O = (u16*)Cout;
        const size_t base = (size_t)(gn >> 6) * (S_LEN * HDIM) + (size_t)(gn & 63);
#pragma unroll
        for (int r = 0; r < 4; ++r)
          O[base + (size_t)(gs0 + r) * HDIM] = f2bs((acc[m][n][r] + bv) * oscale);
      } else if (MODE == 1) {
        u16* O = (u16*)Cout;
        u16 p4[4];
#pragma unroll
        for (int r = 0; r < 4; ++r) p4[r] = f2bs(acc[m][n][r] + bv);
        *reinterpret_cast<uint2*>(O + (size_t)(gn >> 6) * (HDIM * S_LEN) +
                                  (size_t)(gn & 63) * S_LEN + gs0) =
            *reinterpret_cast<const uint2*>(p4);
      } else {
        float* O = (float*)Cout;
#pragma unroll
        for (int r = 0; r < 4; ++r)
          O[(size_t)(gs0 + r) * N + gn] = acc[m][n][r] + bv;
      }
    }
  }
}

__global__ __launch_bounds__(256) void k_gemm_qkv(
    const u16* __restrict__ A,
    const u16* __restrict__ wq, const u16* __restrict__ wk, const u16* __restrict__ wv,
    const float* __restrict__ bq, const float* __restrict__ bk, const float* __restrict__ bv,
    u16* __restrict__ Qo, u16* __restrict__ Ko, u16* __restrict__ Vo) {
  __shared__ __attribute__((aligned(16))) u16 As[128 * 32];
  __shared__ __attribute__((aligned(16))) u16 Bs[128 * 32];
  const int z = blockIdx.z;
  if (z == 0)      gemm_core<0>(As, Bs, A, wq, bq, Qo, CEXP);
  else if (z == 1) gemm_core<0>(As, Bs, A, wk, bk, Ko, 1.f);
  else             gemm_core<1>(As, Bs, A, wv, bv, Vo, 1.f);
}

__global__ __launch_bounds__(256) void k_gemm_o(
    const u16* __restrict__ A, const u16* __restrict__ wo,
    const float* __restrict__ bo, float* __restrict__ out) {
  __shared__ __attribute__((aligned(16))) u16 As[128 * 32];
  __shared__ __attribute__((aligned(16))) u16 Bs[128 * 32];
  gemm_core<2>(As, Bs, A, wo, bo, out, 1.f);
}

// ---- flash attention: Q,K [H][S][64] (Q pre-scaled by CEXP), Vt [H][64][S]
// -> Aout bf16 [S][DM].
// 8-wave blocks, two kv-stream groups (grp = wave>>2): group g handles kv
// tiles 2j+g over the same 128 q-rows. No-max softmax => partials combine by
// plain addition at the end (LDS reduction). Per group: K 2-buf (staged 2
// ahead), V 2-buf (staged 1 ahead), ONE barrier per tile; QK(t+1) MFMA
// overlaps softmax(t) VALU (ping-ponged S accumulators).
__global__ __launch_bounds__(512, 4) void k_attn(
    const u16* __restrict__ Q, const u16* __restrict__ Kg,
    const u16* __restrict__ Vt, u16* __restrict__ Aout) {
  // SM[0][grp][buf] = K tiles, SM[1][grp][buf] = V tiles (8KB each) = 64KB
  __shared__ __attribute__((aligned(16))) u16 SM[2][2][2][64 * 64];

  const int tid = threadIdx.x;
  const int lane = tid & 63, wave = tid >> 6;
  const int grp = wave >> 2, wg = wave & 3;
  const int l31 = lane & 31, lh = lane >> 5;

  // XCD-aware remap: 2 heads per XCD (K/V ~2MB fits one L2)
  const int id = blockIdx.x;
  const int xcd = id & 7, sp = id >> 3;
  const int h = xcd * 2 + (sp & 1);
  const int qb = sp >> 1;
  const int q0 = qb * 128 + wg * 32;

  const u16* Qh = Q + (size_t)h * S_LEN * HDIM;
  const u16* Kh = Kg + (size_t)h * S_LEN * HDIM;
  const u16* Vh = Vt + (size_t)h * HDIM * S_LEN;

  // Q B-frags: col q = l31, k = ks*16 + lh*8 + e
  v8s qf[4];
#pragma unroll
  for (int ks = 0; ks < 4; ++ks)
    qf[ks] = *reinterpret_cast<const v8s*>(
        Qh + (size_t)(q0 + l31) * HDIM + ks * 16 + lh * 8);

  const short ONE = 0x3F80;  // bf16 1.0
  const v8s ones = {ONE, ONE, ONE, ONE, ONE, ONE, ONE, ONE};
  const f32x16 z16 = vzero16();

  f32x16 oacc[2], accl;
  oacc[0] = z16; oacc[1] = z16; accl = z16;

  // staging map: tile [64 rows][8 chunks of 16B], chunk ^= row&7; each group's
  // 4 waves cover the 512 slots (2 gstage calls per wave per tile)
  const int tg = wg * 64 + lane;
  const int s0i = tg, s1i = tg + 256;
  const int r0 = s0i >> 3, c0 = ((s0i & 7) ^ (r0 & 7)) * 8;
  const int r1 = s1i >> 3, c1 = ((s1i & 7) ^ (r1 & 7)) * 8;

  auto stageK = [&](int b, int gt) {   // gt = global kv-tile index
    const int kv0 = gt * 64;
    gstage16(Kh + (size_t)(kv0 + r0) * HDIM + c0, &SM[0][grp][b][(wg * 64) * 8]);
    gstage16(Kh + (size_t)(kv0 + r1) * HDIM + c1, &SM[0][grp][b][(256 + wg * 64) * 8]);
  };
  auto stageV = [&](int b, int gt) {
    const int kv0 = gt * 64;
    gstage16(Vh + (size_t)r0 * S_LEN + kv0 + c0, &SM[1][grp][b][(wg * 64) * 8]);
    gstage16(Vh + (size_t)r1 * S_LEN + kv0 + c1, &SM[1][grp][b][(256 + wg * 64) * 8]);
  };

  // QK into sO from K LDS buffer (C = z16 on first MFMA)
  auto qk = [&](const u16* Kb, f32x16 (&sO)[2]) {
    __builtin_amdgcn_s_setprio(1);
#pragma unroll
    for (int j = 0; j < 2; ++j) {
      const int row = j * 32 + l31;
      v8s k0 = *reinterpret_cast<const v8s*>(
          Kb + (size_t)(row * 8 + ((0 + lh) ^ (row & 7))) * 8);
      sO[j] = __builtin_amdgcn_mfma_f32_32x32x16_bf16(k0, qf[0], z16, 0, 0, 0);
#pragma unroll
      for (int ks = 1; ks < 4; ++ks) {
        v8s kf = *reinterpret_cast<const v8s*>(
            Kb + (size_t)(row * 8 + ((ks * 2 + lh) ^ (row & 7))) * 8);
        sO[j] = __builtin_amdgcn_mfma_f32_32x32x16_bf16(kf, qf[ks], sO[j], 0, 0, 0);
      }
    }
    __builtin_amdgcn_s_setprio(0);
  };

  // body(j): j = group-local tile (global 2j+grp); par = j&1 (static at call)
  // [wait vmcnt(0) barrier] stageK(j+2 -> Kbuf[par]); stageV(j+1 -> Vbuf[par^1]);
  // read V(j) frags from Vbuf[par]; QK(j+1) from Kbuf[par^1]; softmax(j); PV(j)
  auto body = [&](int j, int par, f32x16 (&sIn)[2], f32x16 (&sOut)[2],
                  bool k2, bool n1) {
    asm volatile("s_waitcnt vmcnt(0)\n\ts_barrier" ::: "memory");
    if (k2) stageK(par, 2 * (j + 2) + grp);
    if (n1) stageV(par ^ 1, 2 * (j + 1) + grp);
    if (n1) qk(&SM[0][grp][par ^ 1][0], sOut);

    // V fragment reads: latency hides under the exp/pack VALU
    const u16* Vb = &SM[1][grp][par][0];
    v8s vf[2][4];
#pragma unroll
    for (int n = 0; n < 2; ++n) {
      const int row = n * 32 + l31;
#pragma unroll
      for (int ks = 0; ks < 4; ++ks)
        vf[n][ks] = *reinterpret_cast<const v8s*>(
            Vb + (size_t)(row * 8 + ((ks * 2 + lh) ^ (row & 7))) * 8);
    }

    // softmax(sIn): p = exp2(s); pack to PV A-frags fully in-register
    v8s pf[4];
#pragma unroll
    for (int jj = 0; jj < 2; ++jj) {
      float p[16];
#pragma unroll
      for (int r = 0; r < 16; ++r) p[r] = fexp2(sIn[jj][r]);
      u32 X1, X2, X3, X4, Y1, Y2, Y3, Y4;
      asm("v_cvt_pk_bf16_f32 %0, %1, %2" : "=v"(X1) : "v"(p[0]), "v"(p[1]));
      asm("v_cvt_pk_bf16_f32 %0, %1, %2" : "=v"(Y1) : "v"(p[4]), "v"(p[5]));
      asm("v_cvt_pk_bf16_f32 %0, %1, %2" : "=v"(X2) : "v"(p[2]), "v"(p[3]));
      asm("v_cvt_pk_bf16_f32 %0, %1, %2" : "=v"(Y2) : "v"(p[6]), "v"(p[7]));
      asm("v_cvt_pk_bf16_f32 %0, %1, %2" : "=v"(X3) : "v"(p[8]), "v"(p[9]));
      asm("v_cvt_pk_bf16_f32 %0, %1, %2" : "=v"(Y3) : "v"(p[12]), "v"(p[13]));
      asm("v_cvt_pk_bf16_f32 %0, %1, %2" : "=v"(X4) : "v"(p[10]), "v"(p[11]));
      asm("v_cvt_pk_bf16_f32 %0, %1, %2" : "=v"(Y4) : "v"(p[14]), "v"(p[15]));
      asm("v_permlane32_swap_b32 %0, %1" : "+v"(X1), "+v"(Y1));
      asm("v_permlane32_swap_b32 %0, %1" : "+v"(X2), "+v"(Y2));
      asm("v_permlane32_swap_b32 %0, %1" : "+v"(X3), "+v"(Y3));
      asm("v_permlane32_swap_b32 %0, %1" : "+v"(X4), "+v"(Y4));
      uint4 w0; w0.x = X1; w0.y = X2; w0.z = Y1; w0.w = Y2;
      uint4 w1; w1.x = X3; w1.y = X4; w1.z = Y3; w1.w = Y4;
      pf[jj * 2 + 0] = *reinterpret_cast<const v8s*>(&w0);
      pf[jj * 2 + 1] = *reinterpret_cast<const v8s*>(&w1);
    }

    // PV: O[q][hd] += P[q][kv] @ V[kv][hd]; l[q] += P @ 1
    __builtin_amdgcn_s_setprio(1);
#pragma unroll
    for (int ks = 0; ks < 4; ++ks) {
      accl = __builtin_amdgcn_mfma_f32_32x32x16_bf16(pf[ks], ones, accl, 0, 0, 0);
      oacc[0] = __builtin_amdgcn_mfma_f32_32x32x16_bf16(pf[ks], vf[0][ks], oacc[0], 0, 0, 0);
      oacc[1] = __builtin_amdgcn_mfma_f32_32x32x16_bf16(pf[ks], vf[1][ks], oacc[1], 0, 0, 0);
    }
    __builtin_amdgcn_s_setprio(0);
  };

  constexpr int NTg = S_LEN / 64 / 2;  // 32 tiles per group
  f32x16 sacc0[2], sacc1[2];

  // prologue: K(0)->buf0, K(1)->buf1, V(0)->buf0; wait K(0); QK(0)->sacc0
  stageK(0, grp);
  stageK(1, 2 + grp);
  stageV(0, grp);
  asm volatile("s_waitcnt vmcnt(4)\n\ts_barrier" ::: "memory");
  qk(&SM[0][grp][0][0], sacc0);

  for (int j = 0; j < NTg - 2; j += 2) {
    body(j, 0, sacc0, sacc1, true, true);
    body(j + 1, 1, sacc1, sacc0, true, true);
  }
  body(NTg - 2, 0, sacc0, sacc1, false, true);
  body(NTg - 1, 1, sacc1, sacc0, false, false);

  // cross-group reduction: grp1 -> LDS, grp0 adds. Scratch = SM (48KB used).
  __syncthreads();
  float4* red = (float4*)&SM[0][0][0][0];
  const int wl = wg * 64 + lane;
  if (grp == 1) {
#pragma unroll
    for (int i = 0; i < 4; ++i) {
      float4 a; a.x = oacc[0][4 * i]; a.y = oacc[0][4 * i + 1];
      a.z = oacc[0][4 * i + 2]; a.w = oacc[0][4 * i + 3];
      red[(0 + i) * 256 + wl] = a;
      float4 b; b.x = oacc[1][4 * i]; b.y = oacc[1][4 * i + 1];
      b.z = oacc[1][4 * i + 2]; b.w = oacc[1][4 * i + 3];
      red[(4 + i) * 256 + wl] = b;
      float4 c; c.x = accl[4 * i]; c.y = accl[4 * i + 1];
      c.z = accl[4 * i + 2]; c.w = accl[4 * i + 3];
      red[(8 + i) * 256 + wl] = c;
    }
  }
  __syncthreads();
  if (grp == 0) {
#pragma unroll
    for (int i = 0; i < 4; ++i) {
      float4 a = red[(0 + i) * 256 + wl];
      oacc[0][4 * i] += a.x; oacc[0][4 * i + 1] += a.y;
      oacc[0][4 * i + 2] += a.z; oacc[0][4 * i + 3] += a.w;
      float4 b = red[(4 + i) * 256 + wl];
      oacc[1][4 * i] += b.x; oacc[1][4 * i + 1] += b.y;
      oacc[1][4 * i + 2] += b.z; oacc[1][4 * i + 3] += b.w;
      float4 c = red[(8 + i) * 256 + wl];
      accl[4 * i] += c.x; accl[4 * i + 1] += c.y;
      accl[4 * i + 2] += c.z; accl[4 * i + 3] += c.w;
    }
    // finalize: rows of oacc/accl are q = (r&3) + 8*(r>>2) + 4*lh (+q0)
#pragma unroll
    for (int r = 0; r < 16; ++r) {
      const float inv = __builtin_amdgcn_rcpf(accl[r]);
      const int q = q0 + (r & 3) + 8 * (r >> 2) + 4 * lh;
      const size_t base = (size_t)q * DM + h * HDIM + l31;
      Aout[base] = f2bs(oacc[0][r] * inv);
      Aout[base + 32] = f2bs(oacc[1][r] * inv);
    }
  }
}

// ---- launcher ----------------------------------------------------------
extern "C" void kernel_launch(void* const* d_in, const int* in_sizes, int n_in,
                              void* d_out, int out_size, void* d_ws, size_t ws_size,
                              hipStream_t stream) {
  const float* x  = (const float*)d_in[0];
  const float* wq = (const float*)d_in[1];
  const float* bq = (const float*)d_in[2];
  const float* wk = (const float*)d_in[3];
  const float* bk = (const float*)d_in[4];
  const float* wv = (const float*)d_in[5];
  const float* bv = (const float*)d_in[6];
  const float* wo = (const float*)d_in[7];
  const float* bo = (const float*)d_in[8];
  float* out = (float*)d_out;

  char* ws = (char*)d_ws;
  u16* xb  = (u16*)(ws);                          // [4096][1024] bf16, 8MB
  u16* wqT = (u16*)(ws + (8u << 20));             // [1024][1024] bf16, 2MB each
  u16* wkT = wqT + 1024 * 1024;
  u16* wvT = wkT + 1024 * 1024;
  u16* woT = wvT + 1024 * 1024;
  u16* Qh  = (u16*)(ws + (16u << 20));            // [16][4096][64] bf16, 8MB
  u16* Kh  = Qh + 16 * 4096 * 64;
  u16* Vth = Kh + 16 * 4096 * 64;                 // [16][64][4096]
  u16* Ao  = Vth + 16 * 4096 * 64;                // [4096][1024]

  k_cvt<<<2048, 256, 0, stream>>>(x, xb);
  dim3 tg(32, 32, 4);
  k_wtrans<<<tg, 256, 0, stream>>>(wq, wk, wv, wo, wqT, wkT, wvT, woT);
  dim3 gg(32, 8, 3);
  k_gemm_qkv<<<gg, 256, 0, stream>>>(xb, wqT, wkT, wvT, bq, bk, bv, Qh, Kh, Vth);
  k_attn<<<512, 512, 0, stream>>>(Qh, Kh, Vth, Ao);
  dim3 og(32, 8);
  k_gemm_o<<<og, 256, 0, stream>>>(Ao, woT, bo, out);
}

// Round 7
// 669.667 us; speedup vs baseline: 1.3370x; 1.3370x over previous
//
#include <hip/hip_runtime.h>

typedef unsigned short u16;
typedef unsigned int u32;
typedef short v8s __attribute__((ext_vector_type(8)));
typedef float f32x4 __attribute__((ext_vector_type(4)));
typedef float f32x16 __attribute__((ext_vector_type(16)));

#define S_LEN 4096
#define DM 1024
#define HDIM 64
#define CEXP 0.18033688f /* 0.125 * log2(e), folded into Q at GEMM epilogue */

// ---- helpers ----------------------------------------------------------
__device__ __forceinline__ u16 f2bs(float f) {
  u32 u = __float_as_uint(f);
  u32 r = 0x7FFFu + ((u >> 16) & 1u);
  return (u16)((u + r) >> 16);
}

__device__ __forceinline__ float fexp2(float x) {
  float r;
  asm("v_exp_f32 %0, %1" : "=v"(r) : "v"(x));   // raw 2^x, args bounded
  return r;
}

__device__ __forceinline__ void gstage16(const void* g, void* lds_wave_base) {
  __builtin_amdgcn_global_load_lds(
      (const __attribute__((address_space(1))) u32*)g,
      (__attribute__((address_space(3))) u32*)lds_wave_base, 16, 0, 0);
}

__device__ __forceinline__ f32x16 vzero16() {
  f32x16 v;
#pragma unroll
  for (int r = 0; r < 16; ++r) v[r] = 0.f;
  return v;
}

// ---- elementwise fp32 -> bf16 -----------------------------------------
__global__ void k_cvt(const float* __restrict__ in, u16* __restrict__ out) {
  const int i = blockIdx.x * blockDim.x + threadIdx.x;
  const float4* p = reinterpret_cast<const float4*>(in) + (size_t)i * 2;
  float4 a = p[0], b = p[1];
  u16 t[8] = {f2bs(a.x), f2bs(a.y), f2bs(a.z), f2bs(a.w),
              f2bs(b.x), f2bs(b.y), f2bs(b.z), f2bs(b.w)};
  reinterpret_cast<uint4*>(out)[i] = *reinterpret_cast<const uint4*>(t);
}

// ---- weight transpose+convert: w[K][N] fp32 -> wt[N][K] bf16 ----------
__global__ __launch_bounds__(256) void k_wtrans(
    const float* __restrict__ w0, const float* __restrict__ w1,
    const float* __restrict__ w2, const float* __restrict__ w3,
    u16* __restrict__ t0, u16* __restrict__ t1,
    u16* __restrict__ t2, u16* __restrict__ t3) {
  __shared__ float tile[32][33];
  const float* w; u16* wt;
  switch (blockIdx.z) {
    case 0: w = w0; wt = t0; break;
    case 1: w = w1; wt = t1; break;
    case 2: w = w2; wt = t2; break;
    default: w = w3; wt = t3; break;
  }
  const int r = threadIdx.x >> 3;
  const int c4 = (threadIdx.x & 7) * 4;
  const int k0 = blockIdx.x * 32, n0 = blockIdx.y * 32;
  float4 v = *reinterpret_cast<const float4*>(w + (size_t)(k0 + r) * DM + n0 + c4);
  tile[r][c4] = v.x; tile[r][c4 + 1] = v.y; tile[r][c4 + 2] = v.z; tile[r][c4 + 3] = v.w;
  __syncthreads();
  u16 o4[4] = {f2bs(tile[c4][r]), f2bs(tile[c4 + 1][r]),
               f2bs(tile[c4 + 2][r]), f2bs(tile[c4 + 3][r])};
  *reinterpret_cast<uint2*>(wt + (size_t)(n0 + r) * DM + k0 + c4) =
      *reinterpret_cast<const uint2*>(o4);
}

// ---- GEMM core: C[M=4096,N=1024] = A[bf16, M,K] @ Bt[bf16, N,K]^T + bias
template <int MODE>
__device__ __forceinline__ void gemm_core(
    u16* __restrict__ As, u16* __restrict__ Bs,
    const u16* __restrict__ A, const u16* __restrict__ Bt,
    const float* __restrict__ bias, void* __restrict__ Cout, float oscale) {
  constexpr int K = DM, N = DM;
  const int tid = threadIdx.x;
  const int lane = tid & 63, wave = tid >> 6;
  const int wm = wave >> 1, wn = wave & 1;
  const int l15 = lane & 15, l4 = lane >> 4;
  const int bm0 = blockIdx.x * 128, bn0 = blockIdx.y * 128;

  f32x4 acc[4][4];
#pragma unroll
  for (int m = 0; m < 4; ++m)
#pragma unroll
    for (int n = 0; n < 4; ++n) acc[m][n] = 0.f;

  const int s0 = tid, s1 = tid + 256;
  const int ra0 = s0 >> 2, ca0 = ((s0 & 3) ^ ((ra0 >> 1) & 3)) * 8;
  const int ra1 = s1 >> 2, ca1 = ((s1 & 3) ^ ((ra1 >> 1) & 3)) * 8;
  const u16* Ab = A + (size_t)bm0 * K;
  const u16* Bb = Bt + (size_t)bn0 * K;
  u16* ldsA0 = As + (size_t)(wave * 64) * 8;
  u16* ldsA1 = As + (size_t)(256 + wave * 64) * 8;
  u16* ldsB0 = Bs + (size_t)(wave * 64) * 8;
  u16* ldsB1 = Bs + (size_t)(256 + wave * 64) * 8;

  for (int k0 = 0; k0 < K; k0 += 32) {
    gstage16(Ab + (size_t)ra0 * K + k0 + ca0, ldsA0);
    gstage16(Ab + (size_t)ra1 * K + k0 + ca1, ldsA1);
    gstage16(Bb + (size_t)ra0 * K + k0 + ca0, ldsB0);
    gstage16(Bb + (size_t)ra1 * K + k0 + ca1, ldsB1);
    __syncthreads();
    v8s af[4], bfr[4];
#pragma unroll
    for (int m = 0; m < 4; ++m) {
      const int rowa = wm * 64 + m * 16 + l15;
      af[m] = *reinterpret_cast<const v8s*>(
          As + (size_t)(rowa * 4 + (l4 ^ ((rowa >> 1) & 3))) * 8);
      const int rowb = wn * 64 + m * 16 + l15;
      bfr[m] = *reinterpret_cast<const v8s*>(
          Bs + (size_t)(rowb * 4 + (l4 ^ ((rowb >> 1) & 3))) * 8);
    }
#pragma unroll
    for (int m = 0; m < 4; ++m)
#pragma unroll
      for (int n = 0; n < 4; ++n)
        acc[m][n] = __builtin_amdgcn_mfma_f32_16x16x32_bf16(af[m], bfr[n], acc[m][n], 0, 0, 0);
    __syncthreads();
  }

#pragma unroll
  for (int m = 0; m < 4; ++m) {
    const int gs0 = bm0 + wm * 64 + m * 16 + l4 * 4;
#pragma unroll
    for (int n = 0; n < 4; ++n) {
      const int gn = bn0 + wn * 64 + n * 16 + l15;
      const float bv = bias[gn];
      if (MODE == 0) {
        u16* O = (u16*)Cout;
        const size_t base = (size_t)(gn >> 6) * (S_LEN * HDIM) + (size_t)(gn & 63);
#pragma unroll
        for (int r = 0; r < 4; ++r)
          O[base + (size_t)(gs0 + r) * HDIM] = f2bs((acc[m][n][r] + bv) * oscale);
      } else if (MODE == 1) {
        u16* O = (u16*)Cout;
        u16 p4[4];
#pragma unroll
        for (int r = 0; r < 4; ++r) p4[r] = f2bs(acc[m][n][r] + bv);
        *reinterpret_cast<uint2*>(O + (size_t)(gn >> 6) * (HDIM * S_LEN) +
                                  (size_t)(gn & 63) * S_LEN + gs0) =
            *reinterpret_cast<const uint2*>(p4);
      } else {
        float* O = (float*)Cout;
#pragma unroll
        for (int r = 0; r < 4; ++r)
          O[(size_t)(gs0 + r) * N + gn] = acc[m][n][r] + bv;
      }
    }
  }
}

__global__ __launch_bounds__(256) void k_gemm_qkv(
    const u16* __restrict__ A,
    const u16* __restrict__ wq, const u16* __restrict__ wk, const u16* __restrict__ wv,
    const float* __restrict__ bq, const float* __restrict__ bk, const float* __restrict__ bv,
    u16* __restrict__ Qo, u16* __restrict__ Ko, u16* __restrict__ Vo) {
  __shared__ __attribute__((aligned(16))) u16 As[128 * 32];
  __shared__ __attribute__((aligned(16))) u16 Bs[128 * 32];
  const int z = blockIdx.z;
  if (z == 0)      gemm_core<0>(As, Bs, A, wq, bq, Qo, CEXP);
  else if (z == 1) gemm_core<0>(As, Bs, A, wk, bk, Ko, 1.f);
  else             gemm_core<1>(As, Bs, A, wv, bv, Vo, 1.f);
}

__global__ __launch_bounds__(256) void k_gemm_o(
    const u16* __restrict__ A, const u16* __restrict__ wo,
    const float* __restrict__ bo, float* __restrict__ out) {
  __shared__ __attribute__((aligned(16))) u16 As[128 * 32];
  __shared__ __attribute__((aligned(16))) u16 Bs[128 * 32];
  gemm_core<2>(As, Bs, A, wo, bo, out, 1.f);
}

// ---- flash attention, kv-split: Q,K [H][S][64] (Q pre-scaled by CEXP),
// Vt [H][64][S] -> fp32 partial sums. Grid 1024 = 16h x 32qb x 2 kv-halves;
// each block: 32 kv tiles, 4 waves, K 2-buf (staged 2 ahead) + V 2-buf
// (staged 1 ahead) = 32 KB LDS, VGPR<=128 => 4 blocks/CU (16 waves/CU).
// No-max softmax => halves combine by plain addition (k_reduce).
__global__ __launch_bounds__(256, 4) void k_attn_split(
    const u16* __restrict__ Q, const u16* __restrict__ Kg,
    const u16* __restrict__ Vt, float* __restrict__ Po0,
    float* __restrict__ Po1, float* __restrict__ Pl) {
  __shared__ __attribute__((aligned(16))) u16 Ks[2][64 * 64];
  __shared__ __attribute__((aligned(16))) u16 Vs[2][64 * 64];

  const int tid = threadIdx.x;
  const int lane = tid & 63, wave = tid >> 6;
  const int l31 = lane & 31, lh = lane >> 5;

  // XCD-aware remap: 2 heads per XCD; both kv-halves of (h,qb) on same XCD
  const int id = blockIdx.x;
  const int xcd = id & 7, sp = id >> 3;          // sp: 0..127
  const int h = xcd * 2 + (sp & 1);
  const int qb = (sp >> 1) & 31;
  const int hh = sp >> 6;                        // kv half 0/1
  const int q0 = qb * 128 + wave * 32;
  const int bt = hh * 32;                        // base kv tile

  const u16* Qh = Q + (size_t)h * S_LEN * HDIM;
  const u16* Kh = Kg + (size_t)h * S_LEN * HDIM;
  const u16* Vh = Vt + (size_t)h * HDIM * S_LEN;

  v8s qf[4];
#pragma unroll
  for (int ks = 0; ks < 4; ++ks)
    qf[ks] = *reinterpret_cast<const v8s*>(
        Qh + (size_t)(q0 + l31) * HDIM + ks * 16 + lh * 8);

  const short ONE = 0x3F80;
  const v8s ones = {ONE, ONE, ONE, ONE, ONE, ONE, ONE, ONE};
  const f32x16 z16 = vzero16();

  f32x16 oacc[2], accl;
  oacc[0] = z16; oacc[1] = z16; accl = z16;

  const int s0i = tid, s1i = tid + 256;
  const int r0 = s0i >> 3, c0 = ((s0i & 7) ^ (r0 & 7)) * 8;
  const int r1 = s1i >> 3, c1 = ((s1i & 7) ^ (r1 & 7)) * 8;

  auto stageK = [&](int b, int gt) {
    const int kv0 = gt * 64;
    gstage16(Kh + (size_t)(kv0 + r0) * HDIM + c0, &Ks[b][(wave * 64) * 8]);
    gstage16(Kh + (size_t)(kv0 + r1) * HDIM + c1, &Ks[b][(256 + wave * 64) * 8]);
  };
  auto stageV = [&](int b, int gt) {
    const int kv0 = gt * 64;
    gstage16(Vh + (size_t)r0 * S_LEN + kv0 + c0, &Vs[b][(wave * 64) * 8]);
    gstage16(Vh + (size_t)r1 * S_LEN + kv0 + c1, &Vs[b][(256 + wave * 64) * 8]);
  };

  auto qk = [&](const u16* Kb, f32x16 (&sO)[2]) {
    __builtin_amdgcn_s_setprio(1);
#pragma unroll
    for (int j = 0; j < 2; ++j) {
      const int row = j * 32 + l31;
      v8s k0 = *reinterpret_cast<const v8s*>(
          Kb + (size_t)(row * 8 + ((0 + lh) ^ (row & 7))) * 8);
      sO[j] = __builtin_amdgcn_mfma_f32_32x32x16_bf16(k0, qf[0], z16, 0, 0, 0);
#pragma unroll
      for (int ks = 1; ks < 4; ++ks) {
        v8s kf = *reinterpret_cast<const v8s*>(
            Kb + (size_t)(row * 8 + ((ks * 2 + lh) ^ (row & 7))) * 8);
        sO[j] = __builtin_amdgcn_mfma_f32_32x32x16_bf16(kf, qf[ks], sO[j], 0, 0, 0);
      }
    }
    __builtin_amdgcn_s_setprio(0);
  };

  // body(j): barrier; stageK(j+2 -> Kbuf[j&1]); stageV(j+1 -> Vbuf[(j+1)&1]);
  // qk(j+1) from Kbuf[(j+1)&1]; V frags from Vbuf[j&1]; softmax(j); PV(j)
  auto body = [&](int j, int par, f32x16 (&sIn)[2], f32x16 (&sOut)[2],
                  bool k2, bool n1) {
    asm volatile("s_waitcnt vmcnt(0)\n\ts_barrier" ::: "memory");
    if (k2) stageK(par, bt + j + 2);
    if (n1) stageV(par ^ 1, bt + j + 1);
    if (n1) qk(&Ks[par ^ 1][0], sOut);

    const u16* Vb = &Vs[par][0];
    v8s vf[2][4];
#pragma unroll
    for (int n = 0; n < 2; ++n) {
      const int row = n * 32 + l31;
#pragma unroll
      for (int ks = 0; ks < 4; ++ks)
        vf[n][ks] = *reinterpret_cast<const v8s*>(
            Vb + (size_t)(row * 8 + ((ks * 2 + lh) ^ (row & 7))) * 8);
    }

    v8s pf[4];
#pragma unroll
    for (int jj = 0; jj < 2; ++jj) {
      float p[16];
#pragma unroll
      for (int r = 0; r < 16; ++r) p[r] = fexp2(sIn[jj][r]);
      u32 X1, X2, X3, X4, Y1, Y2, Y3, Y4;
      asm("v_cvt_pk_bf16_f32 %0, %1, %2" : "=v"(X1) : "v"(p[0]), "v"(p[1]));
      asm("v_cvt_pk_bf16_f32 %0, %1, %2" : "=v"(Y1) : "v"(p[4]), "v"(p[5]));
      asm("v_cvt_pk_bf16_f32 %0, %1, %2" : "=v"(X2) : "v"(p[2]), "v"(p[3]));
      asm("v_cvt_pk_bf16_f32 %0, %1, %2" : "=v"(Y2) : "v"(p[6]), "v"(p[7]));
      asm("v_cvt_pk_bf16_f32 %0, %1, %2" : "=v"(X3) : "v"(p[8]), "v"(p[9]));
      asm("v_cvt_pk_bf16_f32 %0, %1, %2" : "=v"(Y3) : "v"(p[12]), "v"(p[13]));
      asm("v_cvt_pk_bf16_f32 %0, %1, %2" : "=v"(X4) : "v"(p[10]), "v"(p[11]));
      asm("v_cvt_pk_bf16_f32 %0, %1, %2" : "=v"(Y4) : "v"(p[14]), "v"(p[15]));
      asm("v_permlane32_swap_b32 %0, %1" : "+v"(X1), "+v"(Y1));
      asm("v_permlane32_swap_b32 %0, %1" : "+v"(X2), "+v"(Y2));
      asm("v_permlane32_swap_b32 %0, %1" : "+v"(X3), "+v"(Y3));
      asm("v_permlane32_swap_b32 %0, %1" : "+v"(X4), "+v"(Y4));
      uint4 w0; w0.x = X1; w0.y = X2; w0.z = Y1; w0.w = Y2;
      uint4 w1; w1.x = X3; w1.y = X4; w1.z = Y3; w1.w = Y4;
      pf[jj * 2 + 0] = *reinterpret_cast<const v8s*>(&w0);
      pf[jj * 2 + 1] = *reinterpret_cast<const v8s*>(&w1);
    }

    __builtin_amdgcn_s_setprio(1);
#pragma unroll
    for (int ks = 0; ks < 4; ++ks) {
      accl = __builtin_amdgcn_mfma_f32_32x32x16_bf16(pf[ks], ones, accl, 0, 0, 0);
      oacc[0] = __builtin_amdgcn_mfma_f32_32x32x16_bf16(pf[ks], vf[0][ks], oacc[0], 0, 0, 0);
      oacc[1] = __builtin_amdgcn_mfma_f32_32x32x16_bf16(pf[ks], vf[1][ks], oacc[1], 0, 0, 0);
    }
    __builtin_amdgcn_s_setprio(0);
  };

  f32x16 sacc0[2], sacc1[2];

  // prologue: K(bt)->b0, K(bt+1)->b1, V(bt)->b0; wait K(bt); QK(0)->sacc0
  stageK(0, bt);
  stageK(1, bt + 1);
  stageV(0, bt);
  asm volatile("s_waitcnt vmcnt(4)\n\ts_barrier" ::: "memory");
  qk(&Ks[0][0], sacc0);

  for (int j = 0; j < 30; j += 2) {
    body(j, 0, sacc0, sacc1, true, true);
    body(j + 1, 1, sacc1, sacc0, true, true);
  }
  body(30, 0, sacc0, sacc1, false, true);
  body(31, 1, sacc1, sacc0, false, false);

  // epilogue: raw fp32 partial sums (no divide)
  float* Po = hh ? Po1 : Po0;
  float* Plh = Pl + (size_t)hh * 16 * S_LEN + (size_t)h * S_LEN;
#pragma unroll
  for (int r = 0; r < 16; ++r) {
    const int q = q0 + (r & 3) + 8 * (r >> 2) + 4 * lh;
    const size_t base = (size_t)q * DM + h * HDIM + l31;
    Po[base] = oacc[0][r];
    Po[base + 32] = oacc[1][r];
    if (l31 == 0) Plh[q] = accl[r];
  }
}

// ---- merge halves: Ao = (Po0 + Po1) / (l0 + l1), bf16 ------------------
__global__ __launch_bounds__(256) void k_reduce(
    const float* __restrict__ Po0, const float* __restrict__ Po1,
    const float* __restrict__ Pl, u16* __restrict__ Ao) {
  const int idx = blockIdx.x * 256 + threadIdx.x;   // 0..524287
  const int q = idx >> 7;
  const int c8 = (idx & 127) << 3;
  const int h = c8 >> 6;
  const float l = Pl[(size_t)h * S_LEN + q] +
                  Pl[(size_t)16 * S_LEN + (size_t)h * S_LEN + q];
  const float inv = 1.f / l;
  const size_t base = (size_t)q * DM + c8;
  const float4* a = reinterpret_cast<const float4*>(Po0 + base);
  const float4* b = reinterpret_cast<const float4*>(Po1 + base);
  float4 a0 = a[0], a1 = a[1], b0 = b[0], b1 = b[1];
  u16 t[8] = {f2bs((a0.x + b0.x) * inv), f2bs((a0.y + b0.y) * inv),
              f2bs((a0.z + b0.z) * inv), f2bs((a0.w + b0.w) * inv),
              f2bs((a1.x + b1.x) * inv), f2bs((a1.y + b1.y) * inv),
              f2bs((a1.z + b1.z) * inv), f2bs((a1.w + b1.w) * inv)};
  *reinterpret_cast<uint4*>(Ao + base) = *reinterpret_cast<const uint4*>(t);
}

// ---- fallback single-pass attention (round-5 kernel, unchanged) --------
__global__ __launch_bounds__(256, 2) void k_attn(
    const u16* __restrict__ Q, const u16* __restrict__ Kg,
    const u16* __restrict__ Vt, u16* __restrict__ Aout) {
  __shared__ __attribute__((aligned(16))) u16 Ks[3][64 * 64];
  __shared__ __attribute__((aligned(16))) u16 Vs[3][64 * 64];

  const int tid = threadIdx.x;
  const int lane = tid & 63, wave = tid >> 6;
  const int l31 = lane & 31, lh = lane >> 5;

  const int id = blockIdx.x;
  const int xcd = id & 7, sp = id >> 3;
  const int h = xcd * 2 + (sp & 1);
  const int qb = sp >> 1;
  const int q0 = qb * 128 + wave * 32;

  const u16* Qh = Q + (size_t)h * S_LEN * HDIM;
  const u16* Kh = Kg + (size_t)h * S_LEN * HDIM;
  const u16* Vh = Vt + (size_t)h * HDIM * S_LEN;

  v8s qf[4];
#pragma unroll
  for (int ks = 0; ks < 4; ++ks)
    qf[ks] = *reinterpret_cast<const v8s*>(
        Qh + (size_t)(q0 + l31) * HDIM + ks * 16 + lh * 8);

  const short ONE = 0x3F80;
  const v8s ones = {ONE, ONE, ONE, ONE, ONE, ONE, ONE, ONE};
  const f32x16 z16 = vzero16();

  f32x16 oacc[2], accl;
  oacc[0] = z16; oacc[1] = z16; accl = z16;

  const int s0i = tid, s1i = tid + 256;
  const int r0 = s0i >> 3, c0 = ((s0i & 7) ^ (r0 & 7)) * 8;
  const int r1 = s1i >> 3, c1 = ((s1i & 7) ^ (r1 & 7)) * 8;

  auto stageKV = [&](int b, int t) {
    const int kv0 = t * 64;
    gstage16(Kh + (size_t)(kv0 + r0) * HDIM + c0, &Ks[b][(wave * 64) * 8]);
    gstage16(Kh + (size_t)(kv0 + r1) * HDIM + c1, &Ks[b][(256 + wave * 64) * 8]);
    gstage16(Vh + (size_t)r0 * S_LEN + kv0 + c0, &Vs[b][(wave * 64) * 8]);
    gstage16(Vh + (size_t)r1 * S_LEN + kv0 + c1, &Vs[b][(256 + wave * 64) * 8]);
  };

  auto qk = [&](const u16* Kb, f32x16 (&sO)[2]) {
    __builtin_amdgcn_s_setprio(1);
#pragma unroll
    for (int j = 0; j < 2; ++j) {
      const int row = j * 32 + l31;
      v8s k0 = *reinterpret_cast<const v8s*>(
          Kb + (size_t)(row * 8 + ((0 + lh) ^ (row & 7))) * 8);
      sO[j] = __builtin_amdgcn_mfma_f32_32x32x16_bf16(k0, qf[0], z16, 0, 0, 0);
#pragma unroll
      for (int ks = 1; ks < 4; ++ks) {
        v8s kf = *reinterpret_cast<const v8s*>(
            Kb + (size_t)(row * 8 + ((ks * 2 + lh) ^ (row & 7))) * 8);
        sO[j] = __builtin_amdgcn_mfma_f32_32x32x16_bf16(kf, qf[ks], sO[j], 0, 0, 0);
      }
    }
    __builtin_amdgcn_s_setprio(0);
  };

  auto body = [&](int t, int ib, f32x16 (&sIn)[2], f32x16 (&sOut)[2],
                  bool hasNext, bool hasNext2) {
    asm volatile("s_waitcnt vmcnt(0)\n\ts_barrier" ::: "memory");
    if (hasNext2) stageKV(ib == 0 ? 2 : ib - 1, t + 2);
    if (hasNext) qk(&Ks[ib == 2 ? 0 : ib + 1][0], sOut);

    const u16* Vb = &Vs[ib][0];
    v8s vf[2][4];
#pragma unroll
    for (int n = 0; n < 2; ++n) {
      const int row = n * 32 + l31;
#pragma unroll
      for (int ks = 0; ks < 4; ++ks)
        vf[n][ks] = *reinterpret_cast<const v8s*>(
            Vb + (size_t)(row * 8 + ((ks * 2 + lh) ^ (row & 7))) * 8);
    }

    v8s pf[4];
#pragma unroll
    for (int jj = 0; jj < 2; ++jj) {
      float p[16];
#pragma unroll
      for (int r = 0; r < 16; ++r) p[r] = fexp2(sIn[jj][r]);
      u32 X1, X2, X3, X4, Y1, Y2, Y3, Y4;
      asm("v_cvt_pk_bf16_f32 %0, %1, %2" : "=v"(X1) : "v"(p[0]), "v"(p[1]));
      asm("v_cvt_pk_bf16_f32 %0, %1, %2" : "=v"(Y1) : "v"(p[4]), "v"(p[5]));
      asm("v_cvt_pk_bf16_f32 %0, %1, %2" : "=v"(X2) : "v"(p[2]), "v"(p[3]));
      asm("v_cvt_pk_bf16_f32 %0, %1, %2" : "=v"(Y2) : "v"(p[6]), "v"(p[7]));
      asm("v_cvt_pk_bf16_f32 %0, %1, %2" : "=v"(X3) : "v"(p[8]), "v"(p[9]));
      asm("v_cvt_pk_bf16_f32 %0, %1, %2" : "=v"(Y3) : "v"(p[12]), "v"(p[13]));
      asm("v_cvt_pk_bf16_f32 %0, %1, %2" : "=v"(X4) : "v"(p[10]), "v"(p[11]));
      asm("v_cvt_pk_bf16_f32 %0, %1, %2" : "=v"(Y4) : "v"(p[14]), "v"(p[15]));
      asm("v_permlane32_swap_b32 %0, %1" : "+v"(X1), "+v"(Y1));
      asm("v_permlane32_swap_b32 %0, %1" : "+v"(X2), "+v"(Y2));
      asm("v_permlane32_swap_b32 %0, %1" : "+v"(X3), "+v"(Y3));
      asm("v_permlane32_swap_b32 %0, %1" : "+v"(X4), "+v"(Y4));
      uint4 w0; w0.x = X1; w0.y = X2; w0.z = Y1; w0.w = Y2;
      uint4 w1; w1.x = X3; w1.y = X4; w1.z = Y3; w1.w = Y4;
      pf[jj * 2 + 0] = *reinterpret_cast<const v8s*>(&w0);
      pf[jj * 2 + 1] = *reinterpret_cast<const v8s*>(&w1);
    }

    __builtin_amdgcn_s_setprio(1);
#pragma unroll
    for (int ks = 0; ks < 4; ++ks) {
      accl = __builtin_amdgcn_mfma_f32_32x32x16_bf16(pf[ks], ones, accl, 0, 0, 0);
      oacc[0] = __builtin_amdgcn_mfma_f32_32x32x16_bf16(pf[ks], vf[0][ks], oacc[0], 0, 0, 0);
      oacc[1] = __builtin_amdgcn_mfma_f32_32x32x16_bf16(pf[ks], vf[1][ks], oacc[1], 0, 0, 0);
    }
    __builtin_amdgcn_s_setprio(0);
  };

  constexpr int NT = S_LEN / 64;
  f32x16 sacc0[2], sacc1[2];

  stageKV(0, 0);
  stageKV(1, 1);
  asm volatile("s_waitcnt vmcnt(4)\n\ts_barrier" ::: "memory");
  qk(&Ks[0][0], sacc0);

  int ib = 0;
  for (int tt = 0; tt < NT - 2; tt += 2) {
    body(tt, ib, sacc0, sacc1, true, true);
    const int ib1 = (ib == 2) ? 0 : ib + 1;
    body(tt + 1, ib1, sacc1, sacc0, true, true);
    ib += 2; if (ib >= 3) ib -= 3;
  }
  body(NT - 2, ib, sacc0, sacc1, true, false);
  const int ibL = (ib == 2) ? 0 : ib + 1;
  body(NT - 1, ibL, sacc1, sacc0, false, false);

#pragma unroll
  for (int r = 0; r < 16; ++r) {
    const float inv = __builtin_amdgcn_rcpf(accl[r]);
    const int q = q0 + (r & 3) + 8 * (r >> 2) + 4 * lh;
    const size_t base = (size_t)q * DM + h * HDIM + l31;
    Aout[base] = f2bs(oacc[0][r] * inv);
    Aout[base + 32] = f2bs(oacc[1][r] * inv);
  }
}

// ---- launcher ----------------------------------------------------------
extern "C" void kernel_launch(void* const* d_in, const int* in_sizes, int n_in,
                              void* d_out, int out_size, void* d_ws, size_t ws_size,
                              hipStream_t stream) {
  const float* x  = (const float*)d_in[0];
  const float* wq = (const float*)d_in[1];
  const float* bq = (const float*)d_in[2];
  const float* wk = (const float*)d_in[3];
  const float* bk = (const float*)d_in[4];
  const float* wv = (const float*)d_in[5];
  const float* bv = (const float*)d_in[6];
  const float* wo = (const float*)d_in[7];
  const float* bo = (const float*)d_in[8];
  float* out = (float*)d_out;

  char* ws = (char*)d_ws;
  u16* xb  = (u16*)(ws);                          // [4096][1024] bf16, 8MB
  u16* wqT = (u16*)(ws + (8u << 20));             // [1024][1024] bf16, 2MB each
  u16* wkT = wqT + 1024 * 1024;
  u16* wvT = wkT + 1024 * 1024;
  u16* woT = wvT + 1024 * 1024;
  u16* Qh  = (u16*)(ws + (16u << 20));            // [16][4096][64] bf16, 8MB
  u16* Kh  = Qh + 16 * 4096 * 64;
  u16* Vth = Kh + 16 * 4096 * 64;                 // [16][64][4096]
  u16* Ao  = Vth + 16 * 4096 * 64;                // [4096][1024] bf16, 8MB @40MB
  float* Po1 = (float*)(ws + (48u << 20));        // [4096][1024] f32, 16MB
  float* Pl  = (float*)(ws + (64u << 20));        // [2][16][4096] f32, 512KB
  const bool split = ws_size >= ((64u << 20) + (1u << 20));

  k_cvt<<<2048, 256, 0, stream>>>(x, xb);
  dim3 tg(32, 32, 4);
  k_wtrans<<<tg, 256, 0, stream>>>(wq, wk, wv, wo, wqT, wkT, wvT, woT);
  dim3 gg(32, 8, 3);
  k_gemm_qkv<<<gg, 256, 0, stream>>>(xb, wqT, wkT, wvT, bq, bk, bv, Qh, Kh, Vth);
  if (split) {
    // half-0 partials go to d_out (free real estate until k_gemm_o)
    k_attn_split<<<1024, 256, 0, stream>>>(Qh, Kh, Vth, out, Po1, Pl);
    k_reduce<<<2048, 256, 0, stream>>>(out, Po1, Pl, Ao);
  } else {
    k_attn<<<512, 256, 0, stream>>>(Qh, Kh, Vth, Ao);
  }
  dim3 og(32, 8);
  k_gemm_o<<<og, 256, 0, stream>>>(Ao, woT, bo, out);
}

// Round 8
// 175.427 us; speedup vs baseline: 5.1038x; 3.8174x over previous
//
#include <hip/hip_runtime.h>

typedef unsigned short u16;
typedef unsigned int u32;
typedef short v8s __attribute__((ext_vector_type(8)));
typedef float f32x4 __attribute__((ext_vector_type(4)));
typedef float f32x16 __attribute__((ext_vector_type(16)));

#define S_LEN 4096
#define DM 1024
#define HDIM 64
#define CEXP 0.18033688f /* 0.125 * log2(e), folded into Q at GEMM epilogue */

// ---- helpers ----------------------------------------------------------
__device__ __forceinline__ u16 f2bs(float f) {
  u32 u = __float_as_uint(f);
  u32 r = 0x7FFFu + ((u >> 16) & 1u);
  return (u16)((u + r) >> 16);
}

__device__ __forceinline__ float fexp2(float x) {
  float r;
  asm("v_exp_f32 %0, %1" : "=v"(r) : "v"(x));   // raw 2^x, args bounded
  return r;
}

__device__ __forceinline__ void gstage16(const void* g, void* lds_wave_base) {
  __builtin_amdgcn_global_load_lds(
      (const __attribute__((address_space(1))) u32*)g,
      (__attribute__((address_space(3))) u32*)lds_wave_base, 16, 0, 0);
}

__device__ __forceinline__ f32x16 vzero16() {
  f32x16 v;
#pragma unroll
  for (int r = 0; r < 16; ++r) v[r] = 0.f;
  return v;
}

// ---- elementwise fp32 -> bf16 -----------------------------------------
__global__ void k_cvt(const float* __restrict__ in, u16* __restrict__ out) {
  const int i = blockIdx.x * blockDim.x + threadIdx.x;
  const float4* p = reinterpret_cast<const float4*>(in) + (size_t)i * 2;
  float4 a = p[0], b = p[1];
  u16 t[8] = {f2bs(a.x), f2bs(a.y), f2bs(a.z), f2bs(a.w),
              f2bs(b.x), f2bs(b.y), f2bs(b.z), f2bs(b.w)};
  reinterpret_cast<uint4*>(out)[i] = *reinterpret_cast<const uint4*>(t);
}

// ---- weight transpose+convert: w[K][N] fp32 -> wt[N][K] bf16 ----------
__global__ __launch_bounds__(256) void k_wtrans(
    const float* __restrict__ w0, const float* __restrict__ w1,
    const float* __restrict__ w2, const float* __restrict__ w3,
    u16* __restrict__ t0, u16* __restrict__ t1,
    u16* __restrict__ t2, u16* __restrict__ t3) {
  __shared__ float tile[32][33];
  const float* w; u16* wt;
  switch (blockIdx.z) {
    case 0: w = w0; wt = t0; break;
    case 1: w = w1; wt = t1; break;
    case 2: w = w2; wt = t2; break;
    default: w = w3; wt = t3; break;
  }
  const int r = threadIdx.x >> 3;
  const int c4 = (threadIdx.x & 7) * 4;
  const int k0 = blockIdx.x * 32, n0 = blockIdx.y * 32;
  float4 v = *reinterpret_cast<const float4*>(w + (size_t)(k0 + r) * DM + n0 + c4);
  tile[r][c4] = v.x; tile[r][c4 + 1] = v.y; tile[r][c4 + 2] = v.z; tile[r][c4 + 3] = v.w;
  __syncthreads();
  u16 o4[4] = {f2bs(tile[c4][r]), f2bs(tile[c4 + 1][r]),
               f2bs(tile[c4 + 2][r]), f2bs(tile[c4 + 3][r])};
  *reinterpret_cast<uint2*>(wt + (size_t)(n0 + r) * DM + k0 + c4) =
      *reinterpret_cast<const uint2*>(o4);
}

// ---- GEMM core: C[M=4096,N=1024] = A[bf16, M,K] @ Bt[bf16, N,K]^T + bias
template <int MODE>
__device__ __forceinline__ void gemm_core(
    u16* __restrict__ As, u16* __restrict__ Bs,
    const u16* __restrict__ A, const u16* __restrict__ Bt,
    const float* __restrict__ bias, void* __restrict__ Cout, float oscale) {
  constexpr int K = DM, N = DM;
  const int tid = threadIdx.x;
  const int lane = tid & 63, wave = tid >> 6;
  const int wm = wave >> 1, wn = wave & 1;
  const int l15 = lane & 15, l4 = lane >> 4;
  const int bm0 = blockIdx.x * 128, bn0 = blockIdx.y * 128;

  f32x4 acc[4][4];
#pragma unroll
  for (int m = 0; m < 4; ++m)
#pragma unroll
    for (int n = 0; n < 4; ++n) acc[m][n] = 0.f;

  const int s0 = tid, s1 = tid + 256;
  const int ra0 = s0 >> 2, ca0 = ((s0 & 3) ^ ((ra0 >> 1) & 3)) * 8;
  const int ra1 = s1 >> 2, ca1 = ((s1 & 3) ^ ((ra1 >> 1) & 3)) * 8;
  const u16* Ab = A + (size_t)bm0 * K;
  const u16* Bb = Bt + (size_t)bn0 * K;
  u16* ldsA0 = As + (size_t)(wave * 64) * 8;
  u16* ldsA1 = As + (size_t)(256 + wave * 64) * 8;
  u16* ldsB0 = Bs + (size_t)(wave * 64) * 8;
  u16* ldsB1 = Bs + (size_t)(256 + wave * 64) * 8;

  for (int k0 = 0; k0 < K; k0 += 32) {
    gstage16(Ab + (size_t)ra0 * K + k0 + ca0, ldsA0);
    gstage16(Ab + (size_t)ra1 * K + k0 + ca1, ldsA1);
    gstage16(Bb + (size_t)ra0 * K + k0 + ca0, ldsB0);
    gstage16(Bb + (size_t)ra1 * K + k0 + ca1, ldsB1);
    __syncthreads();
    v8s af[4], bfr[4];
#pragma unroll
    for (int m = 0; m < 4; ++m) {
      const int rowa = wm * 64 + m * 16 + l15;
      af[m] = *reinterpret_cast<const v8s*>(
          As + (size_t)(rowa * 4 + (l4 ^ ((rowa >> 1) & 3))) * 8);
      const int rowb = wn * 64 + m * 16 + l15;
      bfr[m] = *reinterpret_cast<const v8s*>(
          Bs + (size_t)(rowb * 4 + (l4 ^ ((rowb >> 1) & 3))) * 8);
    }
#pragma unroll
    for (int m = 0; m < 4; ++m)
#pragma unroll
      for (int n = 0; n < 4; ++n)
        acc[m][n] = __builtin_amdgcn_mfma_f32_16x16x32_bf16(af[m], bfr[n], acc[m][n], 0, 0, 0);
    __syncthreads();
  }

#pragma unroll
  for (int m = 0; m < 4; ++m) {
    const int gs0 = bm0 + wm * 64 + m * 16 + l4 * 4;
#pragma unroll
    for (int n = 0; n < 4; ++n) {
      const int gn = bn0 + wn * 64 + n * 16 + l15;
      const float bv = bias[gn];
      if (MODE == 0) {
        u16* O = (u16*)Cout;
        const size_t base = (size_t)(gn >> 6) * (S_LEN * HDIM) + (size_t)(gn & 63);
#pragma unroll
        for (int r = 0; r < 4; ++r)
          O[base + (size_t)(gs0 + r) * HDIM] = f2bs((acc[m][n][r] + bv) * oscale);
      } else if (MODE == 1) {
        u16* O = (u16*)Cout;
        u16 p4[4];
#pragma unroll
        for (int r = 0; r < 4; ++r) p4[r] = f2bs(acc[m][n][r] + bv);
        *reinterpret_cast<uint2*>(O + (size_t)(gn >> 6) * (HDIM * S_LEN) +
                                  (size_t)(gn & 63) * S_LEN + gs0) =
            *reinterpret_cast<const uint2*>(p4);
      } else {
        float* O = (float*)Cout;
#pragma unroll
        for (int r = 0; r < 4; ++r)
          O[(size_t)(gs0 + r) * N + gn] = acc[m][n][r] + bv;
      }
    }
  }
}

__global__ __launch_bounds__(256) void k_gemm_qkv(
    const u16* __restrict__ A,
    const u16* __restrict__ wq, const u16* __restrict__ wk, const u16* __restrict__ wv,
    const float* __restrict__ bq, const float* __restrict__ bk, const float* __restrict__ bv,
    u16* __restrict__ Qo, u16* __restrict__ Ko, u16* __restrict__ Vo) {
  __shared__ __attribute__((aligned(16))) u16 As[128 * 32];
  __shared__ __attribute__((aligned(16))) u16 Bs[128 * 32];
  const int z = blockIdx.z;
  if (z == 0)      gemm_core<0>(As, Bs, A, wq, bq, Qo, CEXP);
  else if (z == 1) gemm_core<0>(As, Bs, A, wk, bk, Ko, 1.f);
  else             gemm_core<1>(As, Bs, A, wv, bv, Vo, 1.f);
}

__global__ __launch_bounds__(256) void k_gemm_o(
    const u16* __restrict__ A, const u16* __restrict__ wo,
    const float* __restrict__ bo, float* __restrict__ out) {
  __shared__ __attribute__((aligned(16))) u16 As[128 * 32];
  __shared__ __attribute__((aligned(16))) u16 Bs[128 * 32];
  gemm_core<2>(As, Bs, A, wo, bo, out, 1.f);
}

// ---- flash attention, kv-split: Q,K [H][S][64] (Q pre-scaled by CEXP),
// Vt [H][64][S] -> fp32 partial sums. Grid 1024 = 16h x 32qb x 2 kv-halves;
// each block: 32 kv tiles, 4 waves, K 2-buf (staged 2 ahead) + V 2-buf
// (staged 1 ahead) = 32 KB LDS. NATURAL register allocation (bounds (256,2)):
// forcing 4 waves/EU spilled catastrophically in r6/r7.
// No-max softmax => halves combine by plain addition (k_reduce).
__global__ __launch_bounds__(256, 2) void k_attn_split(
    const u16* __restrict__ Q, const u16* __restrict__ Kg,
    const u16* __restrict__ Vt, float* __restrict__ Po0,
    float* __restrict__ Po1, float* __restrict__ Pl) {
  __shared__ __attribute__((aligned(16))) u16 Ks[2][64 * 64];
  __shared__ __attribute__((aligned(16))) u16 Vs[2][64 * 64];

  const int tid = threadIdx.x;
  const int lane = tid & 63, wave = tid >> 6;
  const int l31 = lane & 31, lh = lane >> 5;

  // XCD-aware remap: 2 heads per XCD; both kv-halves of (h,qb) on same XCD
  const int id = blockIdx.x;
  const int xcd = id & 7, sp = id >> 3;          // sp: 0..127
  const int h = xcd * 2 + (sp & 1);
  const int qb = (sp >> 1) & 31;
  const int hh = sp >> 6;                        // kv half 0/1
  const int q0 = qb * 128 + wave * 32;
  const int bt = hh * 32;                        // base kv tile

  const u16* Qh = Q + (size_t)h * S_LEN * HDIM;
  const u16* Kh = Kg + (size_t)h * S_LEN * HDIM;
  const u16* Vh = Vt + (size_t)h * HDIM * S_LEN;

  v8s qf[4];
#pragma unroll
  for (int ks = 0; ks < 4; ++ks)
    qf[ks] = *reinterpret_cast<const v8s*>(
        Qh + (size_t)(q0 + l31) * HDIM + ks * 16 + lh * 8);

  const short ONE = 0x3F80;
  const v8s ones = {ONE, ONE, ONE, ONE, ONE, ONE, ONE, ONE};
  const f32x16 z16 = vzero16();

  f32x16 oacc[2], accl;
  oacc[0] = z16; oacc[1] = z16; accl = z16;

  const int s0i = tid, s1i = tid + 256;
  const int r0 = s0i >> 3, c0 = ((s0i & 7) ^ (r0 & 7)) * 8;
  const int r1 = s1i >> 3, c1 = ((s1i & 7) ^ (r1 & 7)) * 8;

  auto stageK = [&](int b, int gt) {
    const int kv0 = gt * 64;
    gstage16(Kh + (size_t)(kv0 + r0) * HDIM + c0, &Ks[b][(wave * 64) * 8]);
    gstage16(Kh + (size_t)(kv0 + r1) * HDIM + c1, &Ks[b][(256 + wave * 64) * 8]);
  };
  auto stageV = [&](int b, int gt) {
    const int kv0 = gt * 64;
    gstage16(Vh + (size_t)r0 * S_LEN + kv0 + c0, &Vs[b][(wave * 64) * 8]);
    gstage16(Vh + (size_t)r1 * S_LEN + kv0 + c1, &Vs[b][(256 + wave * 64) * 8]);
  };

  auto qk = [&](const u16* Kb, f32x16 (&sO)[2]) {
    __builtin_amdgcn_s_setprio(1);
#pragma unroll
    for (int j = 0; j < 2; ++j) {
      const int row = j * 32 + l31;
      v8s k0 = *reinterpret_cast<const v8s*>(
          Kb + (size_t)(row * 8 + ((0 + lh) ^ (row & 7))) * 8);
      sO[j] = __builtin_amdgcn_mfma_f32_32x32x16_bf16(k0, qf[0], z16, 0, 0, 0);
#pragma unroll
      for (int ks = 1; ks < 4; ++ks) {
        v8s kf = *reinterpret_cast<const v8s*>(
            Kb + (size_t)(row * 8 + ((ks * 2 + lh) ^ (row & 7))) * 8);
        sO[j] = __builtin_amdgcn_mfma_f32_32x32x16_bf16(kf, qf[ks], sO[j], 0, 0, 0);
      }
    }
    __builtin_amdgcn_s_setprio(0);
  };

  // body(j): barrier; stageK(j+2 -> Kbuf[j&1]); stageV(j+1 -> Vbuf[(j+1)&1]);
  // qk(j+1) from Kbuf[(j+1)&1]; V frags from Vbuf[j&1]; softmax(j); PV(j)
  auto body = [&](int j, int par, f32x16 (&sIn)[2], f32x16 (&sOut)[2],
                  bool k2, bool n1) {
    asm volatile("s_waitcnt vmcnt(0)\n\ts_barrier" ::: "memory");
    if (k2) stageK(par, bt + j + 2);
    if (n1) stageV(par ^ 1, bt + j + 1);
    if (n1) qk(&Ks[par ^ 1][0], sOut);

    const u16* Vb = &Vs[par][0];
    v8s vf[2][4];
#pragma unroll
    for (int n = 0; n < 2; ++n) {
      const int row = n * 32 + l31;
#pragma unroll
      for (int ks = 0; ks < 4; ++ks)
        vf[n][ks] = *reinterpret_cast<const v8s*>(
            Vb + (size_t)(row * 8 + ((ks * 2 + lh) ^ (row & 7))) * 8);
    }

    v8s pf[4];
#pragma unroll
    for (int jj = 0; jj < 2; ++jj) {
      float p[16];
#pragma unroll
      for (int r = 0; r < 16; ++r) p[r] = fexp2(sIn[jj][r]);
      u32 X1, X2, X3, X4, Y1, Y2, Y3, Y4;
      asm("v_cvt_pk_bf16_f32 %0, %1, %2" : "=v"(X1) : "v"(p[0]), "v"(p[1]));
      asm("v_cvt_pk_bf16_f32 %0, %1, %2" : "=v"(Y1) : "v"(p[4]), "v"(p[5]));
      asm("v_cvt_pk_bf16_f32 %0, %1, %2" : "=v"(X2) : "v"(p[2]), "v"(p[3]));
      asm("v_cvt_pk_bf16_f32 %0, %1, %2" : "=v"(Y2) : "v"(p[6]), "v"(p[7]));
      asm("v_cvt_pk_bf16_f32 %0, %1, %2" : "=v"(X3) : "v"(p[8]), "v"(p[9]));
      asm("v_cvt_pk_bf16_f32 %0, %1, %2" : "=v"(Y3) : "v"(p[12]), "v"(p[13]));
      asm("v_cvt_pk_bf16_f32 %0, %1, %2" : "=v"(X4) : "v"(p[10]), "v"(p[11]));
      asm("v_cvt_pk_bf16_f32 %0, %1, %2" : "=v"(Y4) : "v"(p[14]), "v"(p[15]));
      asm("v_permlane32_swap_b32 %0, %1" : "+v"(X1), "+v"(Y1));
      asm("v_permlane32_swap_b32 %0, %1" : "+v"(X2), "+v"(Y2));
      asm("v_permlane32_swap_b32 %0, %1" : "+v"(X3), "+v"(Y3));
      asm("v_permlane32_swap_b32 %0, %1" : "+v"(X4), "+v"(Y4));
      uint4 w0; w0.x = X1; w0.y = X2; w0.z = Y1; w0.w = Y2;
      uint4 w1; w1.x = X3; w1.y = X4; w1.z = Y3; w1.w = Y4;
      pf[jj * 2 + 0] = *reinterpret_cast<const v8s*>(&w0);
      pf[jj * 2 + 1] = *reinterpret_cast<const v8s*>(&w1);
    }

    __builtin_amdgcn_s_setprio(1);
#pragma unroll
    for (int ks = 0; ks < 4; ++ks) {
      accl = __builtin_amdgcn_mfma_f32_32x32x16_bf16(pf[ks], ones, accl, 0, 0, 0);
      oacc[0] = __builtin_amdgcn_mfma_f32_32x32x16_bf16(pf[ks], vf[0][ks], oacc[0], 0, 0, 0);
      oacc[1] = __builtin_amdgcn_mfma_f32_32x32x16_bf16(pf[ks], vf[1][ks], oacc[1], 0, 0, 0);
    }
    __builtin_amdgcn_s_setprio(0);
  };

  f32x16 sacc0[2], sacc1[2];

  // prologue: K(bt)->b0, K(bt+1)->b1, V(bt)->b0; wait K(bt); QK(0)->sacc0
  stageK(0, bt);
  stageK(1, bt + 1);
  stageV(0, bt);
  asm volatile("s_waitcnt vmcnt(4)\n\ts_barrier" ::: "memory");
  qk(&Ks[0][0], sacc0);

  for (int j = 0; j < 30; j += 2) {
    body(j, 0, sacc0, sacc1, true, true);
    body(j + 1, 1, sacc1, sacc0, true, true);
  }
  body(30, 0, sacc0, sacc1, false, true);
  body(31, 1, sacc1, sacc0, false, false);

  // epilogue: raw fp32 partial sums (no divide)
  float* Po = hh ? Po1 : Po0;
  float* Plh = Pl + (size_t)hh * 16 * S_LEN + (size_t)h * S_LEN;
#pragma unroll
  for (int r = 0; r < 16; ++r) {
    const int q = q0 + (r & 3) + 8 * (r >> 2) + 4 * lh;
    const size_t base = (size_t)q * DM + h * HDIM + l31;
    Po[base] = oacc[0][r];
    Po[base + 32] = oacc[1][r];
    if (l31 == 0) Plh[q] = accl[r];
  }
}

// ---- merge halves: Ao = (Po0 + Po1) / (l0 + l1), bf16 ------------------
__global__ __launch_bounds__(256) void k_reduce(
    const float* __restrict__ Po0, const float* __restrict__ Po1,
    const float* __restrict__ Pl, u16* __restrict__ Ao) {
  const int idx = blockIdx.x * 256 + threadIdx.x;   // 0..524287
  const int q = idx >> 7;
  const int c8 = (idx & 127) << 3;
  const int h = c8 >> 6;
  const float l = Pl[(size_t)h * S_LEN + q] +
                  Pl[(size_t)16 * S_LEN + (size_t)h * S_LEN + q];
  const float inv = 1.f / l;
  const size_t base = (size_t)q * DM + c8;
  const float4* a = reinterpret_cast<const float4*>(Po0 + base);
  const float4* b = reinterpret_cast<const float4*>(Po1 + base);
  float4 a0 = a[0], a1 = a[1], b0 = b[0], b1 = b[1];
  u16 t[8] = {f2bs((a0.x + b0.x) * inv), f2bs((a0.y + b0.y) * inv),
              f2bs((a0.z + b0.z) * inv), f2bs((a0.w + b0.w) * inv),
              f2bs((a1.x + b1.x) * inv), f2bs((a1.y + b1.y) * inv),
              f2bs((a1.z + b1.z) * inv), f2bs((a1.w + b1.w) * inv)};
  *reinterpret_cast<uint4*>(Ao + base) = *reinterpret_cast<const uint4*>(t);
}

// ---- fallback single-pass attention (round-5 kernel, unchanged) --------
__global__ __launch_bounds__(256, 2) void k_attn(
    const u16* __restrict__ Q, const u16* __restrict__ Kg,
    const u16* __restrict__ Vt, u16* __restrict__ Aout) {
  __shared__ __attribute__((aligned(16))) u16 Ks[3][64 * 64];
  __shared__ __attribute__((aligned(16))) u16 Vs[3][64 * 64];

  const int tid = threadIdx.x;
  const int lane = tid & 63, wave = tid >> 6;
  const int l31 = lane & 31, lh = lane >> 5;

  const int id = blockIdx.x;
  const int xcd = id & 7, sp = id >> 3;
  const int h = xcd * 2 + (sp & 1);
  const int qb = sp >> 1;
  const int q0 = qb * 128 + wave * 32;

  const u16* Qh = Q + (size_t)h * S_LEN * HDIM;
  const u16* Kh = Kg + (size_t)h * S_LEN * HDIM;
  const u16* Vh = Vt + (size_t)h * HDIM * S_LEN;

  v8s qf[4];
#pragma unroll
  for (int ks = 0; ks < 4; ++ks)
    qf[ks] = *reinterpret_cast<const v8s*>(
        Qh + (size_t)(q0 + l31) * HDIM + ks * 16 + lh * 8);

  const short ONE = 0x3F80;
  const v8s ones = {ONE, ONE, ONE, ONE, ONE, ONE, ONE, ONE};
  const f32x16 z16 = vzero16();

  f32x16 oacc[2], accl;
  oacc[0] = z16; oacc[1] = z16; accl = z16;

  const int s0i = tid, s1i = tid + 256;
  const int r0 = s0i >> 3, c0 = ((s0i & 7) ^ (r0 & 7)) * 8;
  const int r1 = s1i >> 3, c1 = ((s1i & 7) ^ (r1 & 7)) * 8;

  auto stageKV = [&](int b, int t) {
    const int kv0 = t * 64;
    gstage16(Kh + (size_t)(kv0 + r0) * HDIM + c0, &Ks[b][(wave * 64) * 8]);
    gstage16(Kh + (size_t)(kv0 + r1) * HDIM + c1, &Ks[b][(256 + wave * 64) * 8]);
    gstage16(Vh + (size_t)r0 * S_LEN + kv0 + c0, &Vs[b][(wave * 64) * 8]);
    gstage16(Vh + (size_t)r1 * S_LEN + kv0 + c1, &Vs[b][(256 + wave * 64) * 8]);
  };

  auto qk = [&](const u16* Kb, f32x16 (&sO)[2]) {
    __builtin_amdgcn_s_setprio(1);
#pragma unroll
    for (int j = 0; j < 2; ++j) {
      const int row = j * 32 + l31;
      v8s k0 = *reinterpret_cast<const v8s*>(
          Kb + (size_t)(row * 8 + ((0 + lh) ^ (row & 7))) * 8);
      sO[j] = __builtin_amdgcn_mfma_f32_32x32x16_bf16(k0, qf[0], z16, 0, 0, 0);
#pragma unroll
      for (int ks = 1; ks < 4; ++ks) {
        v8s kf = *reinterpret_cast<const v8s*>(
            Kb + (size_t)(row * 8 + ((ks * 2 + lh) ^ (row & 7))) * 8);
        sO[j] = __builtin_amdgcn_mfma_f32_32x32x16_bf16(kf, qf[ks], sO[j], 0, 0, 0);
      }
    }
    __builtin_amdgcn_s_setprio(0);
  };

  auto body = [&](int t, int ib, f32x16 (&sIn)[2], f32x16 (&sOut)[2],
                  bool hasNext, bool hasNext2) {
    asm volatile("s_waitcnt vmcnt(0)\n\ts_barrier" ::: "memory");
    if (hasNext2) stageKV(ib == 0 ? 2 : ib - 1, t + 2);
    if (hasNext) qk(&Ks[ib == 2 ? 0 : ib + 1][0], sOut);

    const u16* Vb = &Vs[ib][0];
    v8s vf[2][4];
#pragma unroll
    for (int n = 0; n < 2; ++n) {
      const int row = n * 32 + l31;
#pragma unroll
      for (int ks = 0; ks < 4; ++ks)
        vf[n][ks] = *reinterpret_cast<const v8s*>(
            Vb + (size_t)(row * 8 + ((ks * 2 + lh) ^ (row & 7))) * 8);
    }

    v8s pf[4];
#pragma unroll
    for (int jj = 0; jj < 2; ++jj) {
      float p[16];
#pragma unroll
      for (int r = 0; r < 16; ++r) p[r] = fexp2(sIn[jj][r]);
      u32 X1, X2, X3, X4, Y1, Y2, Y3, Y4;
      asm("v_cvt_pk_bf16_f32 %0, %1, %2" : "=v"(X1) : "v"(p[0]), "v"(p[1]));
      asm("v_cvt_pk_bf16_f32 %0, %1, %2" : "=v"(Y1) : "v"(p[4]), "v"(p[5]));
      asm("v_cvt_pk_bf16_f32 %0, %1, %2" : "=v"(X2) : "v"(p[2]), "v"(p[3]));
      asm("v_cvt_pk_bf16_f32 %0, %1, %2" : "=v"(Y2) : "v"(p[6]), "v"(p[7]));
      asm("v_cvt_pk_bf16_f32 %0, %1, %2" : "=v"(X3) : "v"(p[8]), "v"(p[9]));
      asm("v_cvt_pk_bf16_f32 %0, %1, %2" : "=v"(Y3) : "v"(p[12]), "v"(p[13]));
      asm("v_cvt_pk_bf16_f32 %0, %1, %2" : "=v"(X4) : "v"(p[10]), "v"(p[11]));
      asm("v_cvt_pk_bf16_f32 %0, %1, %2" : "=v"(Y4) : "v"(p[14]), "v"(p[15]));
      asm("v_permlane32_swap_b32 %0, %1" : "+v"(X1), "+v"(Y1));
      asm("v_permlane32_swap_b32 %0, %1" : "+v"(X2), "+v"(Y2));
      asm("v_permlane32_swap_b32 %0, %1" : "+v"(X3), "+v"(Y3));
      asm("v_permlane32_swap_b32 %0, %1" : "+v"(X4), "+v"(Y4));
      uint4 w0; w0.x = X1; w0.y = X2; w0.z = Y1; w0.w = Y2;
      uint4 w1; w1.x = X3; w1.y = X4; w1.z = Y3; w1.w = Y4;
      pf[jj * 2 + 0] = *reinterpret_cast<const v8s*>(&w0);
      pf[jj * 2 + 1] = *reinterpret_cast<const v8s*>(&w1);
    }

    __builtin_amdgcn_s_setprio(1);
#pragma unroll
    for (int ks = 0; ks < 4; ++ks) {
      accl = __builtin_amdgcn_mfma_f32_32x32x16_bf16(pf[ks], ones, accl, 0, 0, 0);
      oacc[0] = __builtin_amdgcn_mfma_f32_32x32x16_bf16(pf[ks], vf[0][ks], oacc[0], 0, 0, 0);
      oacc[1] = __builtin_amdgcn_mfma_f32_32x32x16_bf16(pf[ks], vf[1][ks], oacc[1], 0, 0, 0);
    }
    __builtin_amdgcn_s_setprio(0);
  };

  constexpr int NT = S_LEN / 64;
  f32x16 sacc0[2], sacc1[2];

  stageKV(0, 0);
  stageKV(1, 1);
  asm volatile("s_waitcnt vmcnt(4)\n\ts_barrier" ::: "memory");
  qk(&Ks[0][0], sacc0);

  int ib = 0;
  for (int tt = 0; tt < NT - 2; tt += 2) {
    body(tt, ib, sacc0, sacc1, true, true);
    const int ib1 = (ib == 2) ? 0 : ib + 1;
    body(tt + 1, ib1, sacc1, sacc0, true, true);
    ib += 2; if (ib >= 3) ib -= 3;
  }
  body(NT - 2, ib, sacc0, sacc1, true, false);
  const int ibL = (ib == 2) ? 0 : ib + 1;
  body(NT - 1, ibL, sacc1, sacc0, false, false);

#pragma unroll
  for (int r = 0; r < 16; ++r) {
    const float inv = __builtin_amdgcn_rcpf(accl[r]);
    const int q = q0 + (r & 3) + 8 * (r >> 2) + 4 * lh;
    const size_t base = (size_t)q * DM + h * HDIM + l31;
    Aout[base] = f2bs(oacc[0][r] * inv);
    Aout[base + 32] = f2bs(oacc[1][r] * inv);
  }
}

// ---- launcher ----------------------------------------------------------
extern "C" void kernel_launch(void* const* d_in, const int* in_sizes, int n_in,
                              void* d_out, int out_size, void* d_ws, size_t ws_size,
                              hipStream_t stream) {
  const float* x  = (const float*)d_in[0];
  const float* wq = (const float*)d_in[1];
  const float* bq = (const float*)d_in[2];
  const float* wk = (const float*)d_in[3];
  const float* bk = (const float*)d_in[4];
  const float* wv = (const float*)d_in[5];
  const float* bv = (const float*)d_in[6];
  const float* wo = (const float*)d_in[7];
  const float* bo = (const float*)d_in[8];
  float* out = (float*)d_out;

  char* ws = (char*)d_ws;
  u16* xb  = (u16*)(ws);                          // [4096][1024] bf16, 8MB
  u16* wqT = (u16*)(ws + (8u << 20));             // [1024][1024] bf16, 2MB each
  u16* wkT = wqT + 1024 * 1024;
  u16* wvT = wkT + 1024 * 1024;
  u16* woT = wvT + 1024 * 1024;
  u16* Qh  = (u16*)(ws + (16u << 20));            // [16][4096][64] bf16, 8MB
  u16* Kh  = Qh + 16 * 4096 * 64;
  u16* Vth = Kh + 16 * 4096 * 64;                 // [16][64][4096]
  u16* Ao  = Vth + 16 * 4096 * 64;                // [4096][1024] bf16, 8MB @40MB
  float* Po1 = (float*)(ws + (48u << 20));        // [4096][1024] f32, 16MB
  float* Pl  = (float*)(ws + (64u << 20));        // [2][16][4096] f32, 512KB
  const bool split = ws_size >= ((64u << 20) + (1u << 20));

  k_cvt<<<2048, 256, 0, stream>>>(x, xb);
  dim3 tg(32, 32, 4);
  k_wtrans<<<tg, 256, 0, stream>>>(wq, wk, wv, wo, wqT, wkT, wvT, woT);
  dim3 gg(32, 8, 3);
  k_gemm_qkv<<<gg, 256, 0, stream>>>(xb, wqT, wkT, wvT, bq, bk, bv, Qh, Kh, Vth);
  if (split) {
    // half-0 partials go to d_out (free real estate until k_gemm_o)
    k_attn_split<<<1024, 256, 0, stream>>>(Qh, Kh, Vth, out, Po1, Pl);
    k_reduce<<<2048, 256, 0, stream>>>(out, Po1, Pl, Ao);
  } else {
    k_attn<<<512, 256, 0, stream>>>(Qh, Kh, Vth, Ao);
  }
  dim3 og(32, 8);
  k_gemm_o<<<og, 256, 0, stream>>>(Ao, woT, bo, out);
}

// Round 9
// 159.609 us; speedup vs baseline: 5.6096x; 1.0991x over previous
//
#include <hip/hip_runtime.h>

typedef unsigned short u16;
typedef unsigned int u32;
typedef short v8s __attribute__((ext_vector_type(8)));
typedef float f32x4 __attribute__((ext_vector_type(4)));
typedef float f32x16 __attribute__((ext_vector_type(16)));

#define S_LEN 4096
#define DM 1024
#define HDIM 64
#define CEXP 0.18033688f /* 0.125 * log2(e), folded into Q at GEMM epilogue */

// ---- helpers ----------------------------------------------------------
__device__ __forceinline__ u16 f2bs(float f) {
  u32 u = __float_as_uint(f);
  u32 r = 0x7FFFu + ((u >> 16) & 1u);
  return (u16)((u + r) >> 16);
}

__device__ __forceinline__ float fexp2(float x) {
  float r;
  asm("v_exp_f32 %0, %1" : "=v"(r) : "v"(x));   // raw 2^x, args bounded
  return r;
}

__device__ __forceinline__ void gstage16(const void* g, void* lds_wave_base) {
  __builtin_amdgcn_global_load_lds(
      (const __attribute__((address_space(1))) u32*)g,
      (__attribute__((address_space(3))) u32*)lds_wave_base, 16, 0, 0);
}

__device__ __forceinline__ f32x16 vzero16() {
  f32x16 v;
#pragma unroll
  for (int r = 0; r < 16; ++r) v[r] = 0.f;
  return v;
}

// ---- elementwise fp32 -> bf16 -----------------------------------------
__global__ void k_cvt(const float* __restrict__ in, u16* __restrict__ out) {
  const int i = blockIdx.x * blockDim.x + threadIdx.x;
  const float4* p = reinterpret_cast<const float4*>(in) + (size_t)i * 2;
  float4 a = p[0], b = p[1];
  u16 t[8] = {f2bs(a.x), f2bs(a.y), f2bs(a.z), f2bs(a.w),
              f2bs(b.x), f2bs(b.y), f2bs(b.z), f2bs(b.w)};
  reinterpret_cast<uint4*>(out)[i] = *reinterpret_cast<const uint4*>(t);
}

// ---- weight transpose+convert: w[K][N] fp32 -> wt[N][K] bf16 ----------
__global__ __launch_bounds__(256) void k_wtrans(
    const float* __restrict__ w0, const float* __restrict__ w1,
    const float* __restrict__ w2, const float* __restrict__ w3,
    u16* __restrict__ t0, u16* __restrict__ t1,
    u16* __restrict__ t2, u16* __restrict__ t3) {
  __shared__ float tile[32][33];
  const float* w; u16* wt;
  switch (blockIdx.z) {
    case 0: w = w0; wt = t0; break;
    case 1: w = w1; wt = t1; break;
    case 2: w = w2; wt = t2; break;
    default: w = w3; wt = t3; break;
  }
  const int r = threadIdx.x >> 3;
  const int c4 = (threadIdx.x & 7) * 4;
  const int k0 = blockIdx.x * 32, n0 = blockIdx.y * 32;
  float4 v = *reinterpret_cast<const float4*>(w + (size_t)(k0 + r) * DM + n0 + c4);
  tile[r][c4] = v.x; tile[r][c4 + 1] = v.y; tile[r][c4 + 2] = v.z; tile[r][c4 + 3] = v.w;
  __syncthreads();
  u16 o4[4] = {f2bs(tile[c4][r]), f2bs(tile[c4 + 1][r]),
               f2bs(tile[c4 + 2][r]), f2bs(tile[c4 + 3][r])};
  *reinterpret_cast<uint2*>(wt + (size_t)(n0 + r) * DM + k0 + c4) =
      *reinterpret_cast<const uint2*>(o4);
}

// ---- GEMM core: C[M=4096,N=1024] = A[bf16, M,K] @ Bt[bf16, N,K]^T + bias
template <int MODE>
__device__ __forceinline__ void gemm_core(
    u16* __restrict__ As, u16* __restrict__ Bs,
    const u16* __restrict__ A, const u16* __restrict__ Bt,
    const float* __restrict__ bias, void* __restrict__ Cout, float oscale) {
  constexpr int K = DM, N = DM;
  const int tid = threadIdx.x;
  const int lane = tid & 63, wave = tid >> 6;
  const int wm = wave >> 1, wn = wave & 1;
  const int l15 = lane & 15, l4 = lane >> 4;
  const int bm0 = blockIdx.x * 128, bn0 = blockIdx.y * 128;

  f32x4 acc[4][4];
#pragma unroll
  for (int m = 0; m < 4; ++m)
#pragma unroll
    for (int n = 0; n < 4; ++n) acc[m][n] = 0.f;

  const int s0 = tid, s1 = tid + 256;
  const int ra0 = s0 >> 2, ca0 = ((s0 & 3) ^ ((ra0 >> 1) & 3)) * 8;
  const int ra1 = s1 >> 2, ca1 = ((s1 & 3) ^ ((ra1 >> 1) & 3)) * 8;
  const u16* Ab = A + (size_t)bm0 * K;
  const u16* Bb = Bt + (size_t)bn0 * K;
  u16* ldsA0 = As + (size_t)(wave * 64) * 8;
  u16* ldsA1 = As + (size_t)(256 + wave * 64) * 8;
  u16* ldsB0 = Bs + (size_t)(wave * 64) * 8;
  u16* ldsB1 = Bs + (size_t)(256 + wave * 64) * 8;

  for (int k0 = 0; k0 < K; k0 += 32) {
    gstage16(Ab + (size_t)ra0 * K + k0 + ca0, ldsA0);
    gstage16(Ab + (size_t)ra1 * K + k0 + ca1, ldsA1);
    gstage16(Bb + (size_t)ra0 * K + k0 + ca0, ldsB0);
    gstage16(Bb + (size_t)ra1 * K + k0 + ca1, ldsB1);
    __syncthreads();
    v8s af[4], bfr[4];
#pragma unroll
    for (int m = 0; m < 4; ++m) {
      const int rowa = wm * 64 + m * 16 + l15;
      af[m] = *reinterpret_cast<const v8s*>(
          As + (size_t)(rowa * 4 + (l4 ^ ((rowa >> 1) & 3))) * 8);
      const int rowb = wn * 64 + m * 16 + l15;
      bfr[m] = *reinterpret_cast<const v8s*>(
          Bs + (size_t)(rowb * 4 + (l4 ^ ((rowb >> 1) & 3))) * 8);
    }
#pragma unroll
    for (int m = 0; m < 4; ++m)
#pragma unroll
      for (int n = 0; n < 4; ++n)
        acc[m][n] = __builtin_amdgcn_mfma_f32_16x16x32_bf16(af[m], bfr[n], acc[m][n], 0, 0, 0);
    __syncthreads();
  }

#pragma unroll
  for (int m = 0; m < 4; ++m) {
    const int gs0 = bm0 + wm * 64 + m * 16 + l4 * 4;
#pragma unroll
    for (int n = 0; n < 4; ++n) {
      const int gn = bn0 + wn * 64 + n * 16 + l15;
      const float bv = bias[gn];
      if (MODE == 0) {
        u16* O = (u16*)Cout;
        const size_t base = (size_t)(gn >> 6) * (S_LEN * HDIM) + (size_t)(gn & 63);
#pragma unroll
        for (int r = 0; r < 4; ++r)
          O[base + (size_t)(gs0 + r) * HDIM] = f2bs((acc[m][n][r] + bv) * oscale);
      } else if (MODE == 1) {
        u16* O = (u16*)Cout;
        u16 p4[4];
#pragma unroll
        for (int r = 0; r < 4; ++r) p4[r] = f2bs(acc[m][n][r] + bv);
        *reinterpret_cast<uint2*>(O + (size_t)(gn >> 6) * (HDIM * S_LEN) +
                                  (size_t)(gn & 63) * S_LEN + gs0) =
            *reinterpret_cast<const uint2*>(p4);
      } else {
        float* O = (float*)Cout;
#pragma unroll
        for (int r = 0; r < 4; ++r)
          O[(size_t)(gs0 + r) * N + gn] = acc[m][n][r] + bv;
      }
    }
  }
}

__global__ __launch_bounds__(256) void k_gemm_qkv(
    const u16* __restrict__ A,
    const u16* __restrict__ wq, const u16* __restrict__ wk, const u16* __restrict__ wv,
    const float* __restrict__ bq, const float* __restrict__ bk, const float* __restrict__ bv,
    u16* __restrict__ Qo, u16* __restrict__ Ko, u16* __restrict__ Vo) {
  __shared__ __attribute__((aligned(16))) u16 As[128 * 32];
  __shared__ __attribute__((aligned(16))) u16 Bs[128 * 32];
  const int z = blockIdx.z;
  if (z == 0)      gemm_core<0>(As, Bs, A, wq, bq, Qo, CEXP);
  else if (z == 1) gemm_core<0>(As, Bs, A, wk, bk, Ko, 1.f);
  else             gemm_core<1>(As, Bs, A, wv, bv, Vo, 1.f);
}

__global__ __launch_bounds__(256) void k_gemm_o(
    const u16* __restrict__ A, const u16* __restrict__ wo,
    const float* __restrict__ bo, float* __restrict__ out) {
  __shared__ __attribute__((aligned(16))) u16 As[128 * 32];
  __shared__ __attribute__((aligned(16))) u16 Bs[128 * 32];
  gemm_core<2>(As, Bs, A, wo, bo, out, 1.f);
}

// ---- flash attention: Q,K [H][S][64] (Q pre-scaled by CEXP), Vt [H][64][S]
// -> Aout bf16 [S][DM].
// 4-buffer K/V ring, ONE barrier per TWO tiles (body2): writers hit bufs
// (t+2)&3,(t+3)&3 while post-barrier readers touch t&3,(t+1)&3 — disjoint.
// In-wave overlap: SM(t) VALU runs under qk(t+1) MFMAs; SM(t+1) under PV(t).
__global__ __launch_bounds__(256, 2) void k_attn(
    const u16* __restrict__ Q, const u16* __restrict__ Kg,
    const u16* __restrict__ Vt, u16* __restrict__ Aout) {
  __shared__ __attribute__((aligned(16))) u16 Ks[4][64 * 64];
  __shared__ __attribute__((aligned(16))) u16 Vs[4][64 * 64];

  const int tid = threadIdx.x;
  const int lane = tid & 63, wave = tid >> 6;
  const int l31 = lane & 31, lh = lane >> 5;

  // XCD-aware remap: 2 heads per XCD (K/V ~2MB fits one L2)
  const int id = blockIdx.x;
  const int xcd = id & 7, sp = id >> 3;
  const int h = xcd * 2 + (sp & 1);
  const int qb = sp >> 1;
  const int q0 = qb * 128 + wave * 32;

  const u16* Qh = Q + (size_t)h * S_LEN * HDIM;
  const u16* Kh = Kg + (size_t)h * S_LEN * HDIM;
  const u16* Vh = Vt + (size_t)h * HDIM * S_LEN;

  // Q B-frags: col q = l31, k = ks*16 + lh*8 + e
  v8s qf[4];
#pragma unroll
  for (int ks = 0; ks < 4; ++ks)
    qf[ks] = *reinterpret_cast<const v8s*>(
        Qh + (size_t)(q0 + l31) * HDIM + ks * 16 + lh * 8);

  const short ONE = 0x3F80;  // bf16 1.0
  const v8s ones = {ONE, ONE, ONE, ONE, ONE, ONE, ONE, ONE};
  const f32x16 z16 = vzero16();

  f32x16 oacc[2], accl;
  oacc[0] = z16; oacc[1] = z16; accl = z16;

  // staging map: tile [64 rows][8 chunks of 16B], chunk ^= row&7
  const int s0i = tid, s1i = tid + 256;
  const int r0 = s0i >> 3, c0 = ((s0i & 7) ^ (r0 & 7)) * 8;
  const int r1 = s1i >> 3, c1 = ((s1i & 7) ^ (r1 & 7)) * 8;

  auto stageKV = [&](int b, int t) {
    const int kv0 = t * 64;
    gstage16(Kh + (size_t)(kv0 + r0) * HDIM + c0, &Ks[b][(wave * 64) * 8]);
    gstage16(Kh + (size_t)(kv0 + r1) * HDIM + c1, &Ks[b][(256 + wave * 64) * 8]);
    gstage16(Vh + (size_t)r0 * S_LEN + kv0 + c0, &Vs[b][(wave * 64) * 8]);
    gstage16(Vh + (size_t)r1 * S_LEN + kv0 + c1, &Vs[b][(256 + wave * 64) * 8]);
  };

  // QK into sO from K LDS buffer (C = z16 on first MFMA)
  auto qk = [&](const u16* Kb, f32x16 (&sO)[2]) {
    __builtin_amdgcn_s_setprio(1);
#pragma unroll
    for (int j = 0; j < 2; ++j) {
      const int row = j * 32 + l31;
      v8s k0 = *reinterpret_cast<const v8s*>(
          Kb + (size_t)(row * 8 + ((0 + lh) ^ (row & 7))) * 8);
      sO[j] = __builtin_amdgcn_mfma_f32_32x32x16_bf16(k0, qf[0], z16, 0, 0, 0);
#pragma unroll
      for (int ks = 1; ks < 4; ++ks) {
        v8s kf = *reinterpret_cast<const v8s*>(
            Kb + (size_t)(row * 8 + ((ks * 2 + lh) ^ (row & 7))) * 8);
        sO[j] = __builtin_amdgcn_mfma_f32_32x32x16_bf16(kf, qf[ks], sO[j], 0, 0, 0);
      }
    }
    __builtin_amdgcn_s_setprio(0);
  };

  // one tile's softmax + PV from sacc (scores) and V buffer
  auto halfTile = [&](const u16* Vb, f32x16 (&sIn)[2]) {
    v8s vf[2][4];
#pragma unroll
    for (int n = 0; n < 2; ++n) {
      const int row = n * 32 + l31;
#pragma unroll
      for (int ks = 0; ks < 4; ++ks)
        vf[n][ks] = *reinterpret_cast<const v8s*>(
            Vb + (size_t)(row * 8 + ((ks * 2 + lh) ^ (row & 7))) * 8);
    }

    v8s pf[4];
#pragma unroll
    for (int jj = 0; jj < 2; ++jj) {
      float p[16];
#pragma unroll
      for (int r = 0; r < 16; ++r) p[r] = fexp2(sIn[jj][r]);
      u32 X1, X2, X3, X4, Y1, Y2, Y3, Y4;
      asm("v_cvt_pk_bf16_f32 %0, %1, %2" : "=v"(X1) : "v"(p[0]), "v"(p[1]));
      asm("v_cvt_pk_bf16_f32 %0, %1, %2" : "=v"(Y1) : "v"(p[4]), "v"(p[5]));
      asm("v_cvt_pk_bf16_f32 %0, %1, %2" : "=v"(X2) : "v"(p[2]), "v"(p[3]));
      asm("v_cvt_pk_bf16_f32 %0, %1, %2" : "=v"(Y2) : "v"(p[6]), "v"(p[7]));
      asm("v_cvt_pk_bf16_f32 %0, %1, %2" : "=v"(X3) : "v"(p[8]), "v"(p[9]));
      asm("v_cvt_pk_bf16_f32 %0, %1, %2" : "=v"(Y3) : "v"(p[12]), "v"(p[13]));
      asm("v_cvt_pk_bf16_f32 %0, %1, %2" : "=v"(X4) : "v"(p[10]), "v"(p[11]));
      asm("v_cvt_pk_bf16_f32 %0, %1, %2" : "=v"(Y4) : "v"(p[14]), "v"(p[15]));
      asm("v_permlane32_swap_b32 %0, %1" : "+v"(X1), "+v"(Y1));
      asm("v_permlane32_swap_b32 %0, %1" : "+v"(X2), "+v"(Y2));
      asm("v_permlane32_swap_b32 %0, %1" : "+v"(X3), "+v"(Y3));
      asm("v_permlane32_swap_b32 %0, %1" : "+v"(X4), "+v"(Y4));
      uint4 w0; w0.x = X1; w0.y = X2; w0.z = Y1; w0.w = Y2;
      uint4 w1; w1.x = X3; w1.y = X4; w1.z = Y3; w1.w = Y4;
      pf[jj * 2 + 0] = *reinterpret_cast<const v8s*>(&w0);
      pf[jj * 2 + 1] = *reinterpret_cast<const v8s*>(&w1);
    }

    __builtin_amdgcn_s_setprio(1);
#pragma unroll
    for (int ks = 0; ks < 4; ++ks) {
      accl = __builtin_amdgcn_mfma_f32_32x32x16_bf16(pf[ks], ones, accl, 0, 0, 0);
      oacc[0] = __builtin_amdgcn_mfma_f32_32x32x16_bf16(pf[ks], vf[0][ks], oacc[0], 0, 0, 0);
      oacc[1] = __builtin_amdgcn_mfma_f32_32x32x16_bf16(pf[ks], vf[1][ks], oacc[1], 0, 0, 0);
    }
    __builtin_amdgcn_s_setprio(0);
  };

  f32x16 sacc0[2], sacc1[2];

  // body2(t): [vmcnt(0)+barrier]; stage(t+2 -> b2, t+3 -> b3);
  // qk(t from b0)->sacc0; qk(t+1 from b1)->sacc1; half(t); half(t+1)
  auto body2 = [&](int t, int b0, int b1, int b2, int b3, bool doStage) {
    asm volatile("s_waitcnt vmcnt(0)\n\ts_barrier" ::: "memory");
    if (doStage) { stageKV(b2, t + 2); stageKV(b3, t + 3); }
    qk(&Ks[b0][0], sacc0);
    qk(&Ks[b1][0], sacc1);
    halfTile(&Vs[b0][0], sacc0);
    halfTile(&Vs[b1][0], sacc1);
  };

  // prologue: stage tiles 0,1
  stageKV(0, 0);
  stageKV(1, 1);

  for (int tt = 0; tt < 60; tt += 4) {
    body2(tt, 0, 1, 2, 3, true);
    body2(tt + 2, 2, 3, 0, 1, true);
  }
  body2(60, 0, 1, 2, 3, true);    // stages 62,63
  body2(62, 2, 3, 0, 1, false);   // last pair, no staging

  // finalize: rows of oacc/accl are q = (r&3) + 8*(r>>2) + 4*lh (+q0)
#pragma unroll
  for (int r = 0; r < 16; ++r) {
    const float inv = __builtin_amdgcn_rcpf(accl[r]);
    const int q = q0 + (r & 3) + 8 * (r >> 2) + 4 * lh;
    const size_t base = (size_t)q * DM + h * HDIM + l31;
    Aout[base] = f2bs(oacc[0][r] * inv);
    Aout[base + 32] = f2bs(oacc[1][r] * inv);
  }
}

// ---- launcher ----------------------------------------------------------
extern "C" void kernel_launch(void* const* d_in, const int* in_sizes, int n_in,
                              void* d_out, int out_size, void* d_ws, size_t ws_size,
                              hipStream_t stream) {
  const float* x  = (const float*)d_in[0];
  const float* wq = (const float*)d_in[1];
  const float* bq = (const float*)d_in[2];
  const float* wk = (const float*)d_in[3];
  const float* bk = (const float*)d_in[4];
  const float* wv = (const float*)d_in[5];
  const float* bv = (const float*)d_in[6];
  const float* wo = (const float*)d_in[7];
  const float* bo = (const float*)d_in[8];
  float* out = (float*)d_out;

  char* ws = (char*)d_ws;
  u16* xb  = (u16*)(ws);                          // [4096][1024] bf16, 8MB
  u16* wqT = (u16*)(ws + (8u << 20));             // [1024][1024] bf16, 2MB each
  u16* wkT = wqT + 1024 * 1024;
  u16* wvT = wkT + 1024 * 1024;
  u16* woT = wvT + 1024 * 1024;
  u16* Qh  = (u16*)(ws + (16u << 20));            // [16][4096][64] bf16, 8MB
  u16* Kh  = Qh + 16 * 4096 * 64;
  u16* Vth = Kh + 16 * 4096 * 64;                 // [16][64][4096]
  u16* Ao  = Vth + 16 * 4096 * 64;                // [4096][1024]

  k_cvt<<<2048, 256, 0, stream>>>(x, xb);
  dim3 tg(32, 32, 4);
  k_wtrans<<<tg, 256, 0, stream>>>(wq, wk, wv, wo, wqT, wkT, wvT, woT);
  dim3 gg(32, 8, 3);
  k_gemm_qkv<<<gg, 256, 0, stream>>>(xb, wqT, wkT, wvT, bq, bk, bv, Qh, Kh, Vth);
  k_attn<<<512, 256, 0, stream>>>(Qh, Kh, Vth, Ao);
  dim3 og(32, 8);
  k_gemm_o<<<og, 256, 0, stream>>>(Ao, woT, bo, out);
}

// Round 10
// 153.260 us; speedup vs baseline: 5.8420x; 1.0414x over previous
//
#include <hip/hip_runtime.h>

typedef unsigned short u16;
typedef unsigned int u32;
typedef short v8s __attribute__((ext_vector_type(8)));
typedef float f32x4 __attribute__((ext_vector_type(4)));
typedef float f32x16 __attribute__((ext_vector_type(16)));

#define S_LEN 4096
#define DM 1024
#define HDIM 64
#define CEXP 0.18033688f /* 0.125 * log2(e), folded into Q at GEMM epilogue */

// ---- helpers ----------------------------------------------------------
__device__ __forceinline__ u16 f2bs(float f) {
  u32 u = __float_as_uint(f);
  u32 r = 0x7FFFu + ((u >> 16) & 1u);
  return (u16)((u + r) >> 16);
}

__device__ __forceinline__ float fexp2(float x) {
  float r;
  asm("v_exp_f32 %0, %1" : "=v"(r) : "v"(x));   // raw 2^x, args bounded
  return r;
}

__device__ __forceinline__ void gstage16(const void* g, void* lds_wave_base) {
  __builtin_amdgcn_global_load_lds(
      (const __attribute__((address_space(1))) u32*)g,
      (__attribute__((address_space(3))) u32*)lds_wave_base, 16, 0, 0);
}

__device__ __forceinline__ f32x16 vzero16() {
  f32x16 v;
#pragma unroll
  for (int r = 0; r < 16; ++r) v[r] = 0.f;
  return v;
}

// ---- fused prep: 4x weight transpose+cvt, plus x fp32->bf16 ------------
// grid (32,32,6): z<4 -> wtrans w[z]; z in {4,5} -> cvt slice
__global__ __launch_bounds__(256) void k_prep(
    const float* __restrict__ x,
    const float* __restrict__ w0, const float* __restrict__ w1,
    const float* __restrict__ w2, const float* __restrict__ w3,
    u16* __restrict__ xb,
    u16* __restrict__ t0, u16* __restrict__ t1,
    u16* __restrict__ t2, u16* __restrict__ t3) {
  const int z = blockIdx.z;
  if (z < 4) {
    __shared__ float tile[32][33];
    const float* w; u16* wt;
    switch (z) {
      case 0: w = w0; wt = t0; break;
      case 1: w = w1; wt = t1; break;
      case 2: w = w2; wt = t2; break;
      default: w = w3; wt = t3; break;
    }
    const int r = threadIdx.x >> 3;
    const int c4 = (threadIdx.x & 7) * 4;
    const int k0 = blockIdx.x * 32, n0 = blockIdx.y * 32;
    float4 v = *reinterpret_cast<const float4*>(w + (size_t)(k0 + r) * DM + n0 + c4);
    tile[r][c4] = v.x; tile[r][c4 + 1] = v.y; tile[r][c4 + 2] = v.z; tile[r][c4 + 3] = v.w;
    __syncthreads();
    u16 o4[4] = {f2bs(tile[c4][r]), f2bs(tile[c4 + 1][r]),
                 f2bs(tile[c4 + 2][r]), f2bs(tile[c4 + 3][r])};
    *reinterpret_cast<uint2*>(wt + (size_t)(n0 + r) * DM + k0 + c4) =
        *reinterpret_cast<const uint2*>(o4);
  } else {
    const int ci = ((z - 4) * 1024 + blockIdx.y * 32 + blockIdx.x) * 256 + threadIdx.x;
    const float4* p = reinterpret_cast<const float4*>(x) + (size_t)ci * 2;
    float4 a = p[0], b = p[1];
    u16 t[8] = {f2bs(a.x), f2bs(a.y), f2bs(a.z), f2bs(a.w),
                f2bs(b.x), f2bs(b.y), f2bs(b.z), f2bs(b.w)};
    reinterpret_cast<uint4*>(xb)[ci] = *reinterpret_cast<const uint4*>(t);
  }
}

// ---- GEMM core (128x128): C = A[M,K] @ Bt[N,K]^T + bias ----------------
template <int MODE>
__device__ __forceinline__ void gemm_core(
    u16* __restrict__ As, u16* __restrict__ Bs,
    const u16* __restrict__ A, const u16* __restrict__ Bt,
    const float* __restrict__ bias, void* __restrict__ Cout, float oscale) {
  constexpr int K = DM;
  const int tid = threadIdx.x;
  const int lane = tid & 63, wave = tid >> 6;
  const int wm = wave >> 1, wn = wave & 1;
  const int l15 = lane & 15, l4 = lane >> 4;
  const int bm0 = blockIdx.x * 128, bn0 = blockIdx.y * 128;

  f32x4 acc[4][4];
#pragma unroll
  for (int m = 0; m < 4; ++m)
#pragma unroll
    for (int n = 0; n < 4; ++n) acc[m][n] = 0.f;

  const int s0 = tid, s1 = tid + 256;
  const int ra0 = s0 >> 2, ca0 = ((s0 & 3) ^ ((ra0 >> 1) & 3)) * 8;
  const int ra1 = s1 >> 2, ca1 = ((s1 & 3) ^ ((ra1 >> 1) & 3)) * 8;
  const u16* Ab = A + (size_t)bm0 * K;
  const u16* Bb = Bt + (size_t)bn0 * K;
  u16* ldsA0 = As + (size_t)(wave * 64) * 8;
  u16* ldsA1 = As + (size_t)(256 + wave * 64) * 8;
  u16* ldsB0 = Bs + (size_t)(wave * 64) * 8;
  u16* ldsB1 = Bs + (size_t)(256 + wave * 64) * 8;

  for (int k0 = 0; k0 < K; k0 += 32) {
    gstage16(Ab + (size_t)ra0 * K + k0 + ca0, ldsA0);
    gstage16(Ab + (size_t)ra1 * K + k0 + ca1, ldsA1);
    gstage16(Bb + (size_t)ra0 * K + k0 + ca0, ldsB0);
    gstage16(Bb + (size_t)ra1 * K + k0 + ca1, ldsB1);
    __syncthreads();
    v8s af[4], bfr[4];
#pragma unroll
    for (int m = 0; m < 4; ++m) {
      const int rowa = wm * 64 + m * 16 + l15;
      af[m] = *reinterpret_cast<const v8s*>(
          As + (size_t)(rowa * 4 + (l4 ^ ((rowa >> 1) & 3))) * 8);
      const int rowb = wn * 64 + m * 16 + l15;
      bfr[m] = *reinterpret_cast<const v8s*>(
          Bs + (size_t)(rowb * 4 + (l4 ^ ((rowb >> 1) & 3))) * 8);
    }
#pragma unroll
    for (int m = 0; m < 4; ++m)
#pragma unroll
      for (int n = 0; n < 4; ++n)
        acc[m][n] = __builtin_amdgcn_mfma_f32_16x16x32_bf16(af[m], bfr[n], acc[m][n], 0, 0, 0);
    __syncthreads();
  }

#pragma unroll
  for (int m = 0; m < 4; ++m) {
    const int gs0 = bm0 + wm * 64 + m * 16 + l4 * 4;
#pragma unroll
    for (int n = 0; n < 4; ++n) {
      const int gn = bn0 + wn * 64 + n * 16 + l15;
      const float bv = bias[gn];
      if (MODE == 0) {
        u16* O = (u16*)Cout;
        const size_t base = (size_t)(gn >> 6) * (S_LEN * HDIM) + (size_t)(gn & 63);
#pragma unroll
        for (int r = 0; r < 4; ++r)
          O[base + (size_t)(gs0 + r) * HDIM] = f2bs((acc[m][n][r] + bv) * oscale);
      } else {
        u16* O = (u16*)Cout;
        u16 p4[4];
#pragma unroll
        for (int r = 0; r < 4; ++r) p4[r] = f2bs(acc[m][n][r] + bv);
        *reinterpret_cast<uint2*>(O + (size_t)(gn >> 6) * (HDIM * S_LEN) +
                                  (size_t)(gn & 63) * S_LEN + gs0) =
            *reinterpret_cast<const uint2*>(p4);
      }
    }
  }
}

__global__ __launch_bounds__(256) void k_gemm_qkv(
    const u16* __restrict__ A,
    const u16* __restrict__ wq, const u16* __restrict__ wk, const u16* __restrict__ wv,
    const float* __restrict__ bq, const float* __restrict__ bk, const float* __restrict__ bv,
    u16* __restrict__ Qo, u16* __restrict__ Ko, u16* __restrict__ Vo) {
  __shared__ __attribute__((aligned(16))) u16 As[128 * 32];
  __shared__ __attribute__((aligned(16))) u16 Bs[128 * 32];
  const int z = blockIdx.z;
  if (z == 0)      gemm_core<0>(As, Bs, A, wq, bq, Qo, CEXP);
  else if (z == 1) gemm_core<0>(As, Bs, A, wk, bk, Ko, 1.f);
  else             gemm_core<1>(As, Bs, A, wv, bv, Vo, 1.f);
}

// ---- output GEMM, 128x64 tiles: grid (32,16) = 512 blocks = 2/CU -------
__global__ __launch_bounds__(256) void k_gemm_o(
    const u16* __restrict__ A, const u16* __restrict__ wo,
    const float* __restrict__ bo, float* __restrict__ out) {
  __shared__ __attribute__((aligned(16))) u16 As[128 * 32];
  __shared__ __attribute__((aligned(16))) u16 Bs[64 * 32];
  constexpr int K = DM, N = DM;
  const int tid = threadIdx.x;
  const int lane = tid & 63, wave = tid >> 6;
  const int wm = wave >> 1, wn = wave & 1;
  const int l15 = lane & 15, l4 = lane >> 4;
  const int bm0 = blockIdx.x * 128, bn0 = blockIdx.y * 64;

  f32x4 acc[4][2];
#pragma unroll
  for (int m = 0; m < 4; ++m)
#pragma unroll
    for (int n = 0; n < 2; ++n) acc[m][n] = 0.f;

  const int s0 = tid, s1 = tid + 256;
  const int ra0 = s0 >> 2, ca0 = ((s0 & 3) ^ ((ra0 >> 1) & 3)) * 8;
  const int ra1 = s1 >> 2, ca1 = ((s1 & 3) ^ ((ra1 >> 1) & 3)) * 8;
  const int rb = tid >> 2,  cb = ((tid & 3) ^ ((rb >> 1) & 3)) * 8;
  const u16* Ab = A + (size_t)bm0 * K;
  const u16* Bb = wo + (size_t)bn0 * K;
  u16* ldsA0 = As + (size_t)(wave * 64) * 8;
  u16* ldsA1 = As + (size_t)(256 + wave * 64) * 8;
  u16* ldsB0 = Bs + (size_t)(wave * 64) * 8;

  for (int k0 = 0; k0 < K; k0 += 32) {
    gstage16(Ab + (size_t)ra0 * K + k0 + ca0, ldsA0);
    gstage16(Ab + (size_t)ra1 * K + k0 + ca1, ldsA1);
    gstage16(Bb + (size_t)rb * K + k0 + cb, ldsB0);
    __syncthreads();
    v8s af[4], bfr[2];
#pragma unroll
    for (int m = 0; m < 4; ++m) {
      const int rowa = wm * 64 + m * 16 + l15;
      af[m] = *reinterpret_cast<const v8s*>(
          As + (size_t)(rowa * 4 + (l4 ^ ((rowa >> 1) & 3))) * 8);
    }
#pragma unroll
    for (int n = 0; n < 2; ++n) {
      const int rowb = wn * 32 + n * 16 + l15;
      bfr[n] = *reinterpret_cast<const v8s*>(
          Bs + (size_t)(rowb * 4 + (l4 ^ ((rowb >> 1) & 3))) * 8);
    }
#pragma unroll
    for (int m = 0; m < 4; ++m)
#pragma unroll
      for (int n = 0; n < 2; ++n)
        acc[m][n] = __builtin_amdgcn_mfma_f32_16x16x32_bf16(af[m], bfr[n], acc[m][n], 0, 0, 0);
    __syncthreads();
  }

#pragma unroll
  for (int m = 0; m < 4; ++m) {
    const int gs0 = bm0 + wm * 64 + m * 16 + l4 * 4;
#pragma unroll
    for (int n = 0; n < 2; ++n) {
      const int gn = bn0 + wn * 32 + n * 16 + l15;
      const float bv = bo[gn];
#pragma unroll
      for (int r = 0; r < 4; ++r)
        out[(size_t)(gs0 + r) * N + gn] = acc[m][n][r] + bv;
    }
  }
}

// ---- flash attention: Q,K [H][S][64] (Q pre-scaled by CEXP), Vt [H][64][S]
// -> Aout bf16 [S][DM].
// 4-buffer K/V ring, ONE barrier per TWO tiles. Denominator now via VALU
// (lsum accumulated in the exp loop; one permlane32_swap at finalize) —
// removes the 4 ones-MFMAs per tile and frees 16 AGPR.
__global__ __launch_bounds__(256, 2) void k_attn(
    const u16* __restrict__ Q, const u16* __restrict__ Kg,
    const u16* __restrict__ Vt, u16* __restrict__ Aout) {
  __shared__ __attribute__((aligned(16))) u16 Ks[4][64 * 64];
  __shared__ __attribute__((aligned(16))) u16 Vs[4][64 * 64];

  const int tid = threadIdx.x;
  const int lane = tid & 63, wave = tid >> 6;
  const int l31 = lane & 31, lh = lane >> 5;

  // XCD-aware remap: 2 heads per XCD (K/V ~2MB fits one L2)
  const int id = blockIdx.x;
  const int xcd = id & 7, sp = id >> 3;
  const int h = xcd * 2 + (sp & 1);
  const int qb = sp >> 1;
  const int q0 = qb * 128 + wave * 32;

  const u16* Qh = Q + (size_t)h * S_LEN * HDIM;
  const u16* Kh = Kg + (size_t)h * S_LEN * HDIM;
  const u16* Vh = Vt + (size_t)h * HDIM * S_LEN;

  // Q B-frags: col q = l31, k = ks*16 + lh*8 + e
  v8s qf[4];
#pragma unroll
  for (int ks = 0; ks < 4; ++ks)
    qf[ks] = *reinterpret_cast<const v8s*>(
        Qh + (size_t)(q0 + l31) * HDIM + ks * 16 + lh * 8);

  const f32x16 z16 = vzero16();
  f32x16 oacc[2];
  oacc[0] = z16; oacc[1] = z16;
  float lsum = 0.f;   // denominator partial: q = l31, kv-half = lh

  // staging map: tile [64 rows][8 chunks of 16B], chunk ^= row&7
  const int s0i = tid, s1i = tid + 256;
  const int r0 = s0i >> 3, c0 = ((s0i & 7) ^ (r0 & 7)) * 8;
  const int r1 = s1i >> 3, c1 = ((s1i & 7) ^ (r1 & 7)) * 8;

  auto stageKV = [&](int b, int t) {
    const int kv0 = t * 64;
    gstage16(Kh + (size_t)(kv0 + r0) * HDIM + c0, &Ks[b][(wave * 64) * 8]);
    gstage16(Kh + (size_t)(kv0 + r1) * HDIM + c1, &Ks[b][(256 + wave * 64) * 8]);
    gstage16(Vh + (size_t)r0 * S_LEN + kv0 + c0, &Vs[b][(wave * 64) * 8]);
    gstage16(Vh + (size_t)r1 * S_LEN + kv0 + c1, &Vs[b][(256 + wave * 64) * 8]);
  };

  // QK into sO from K LDS buffer (C = z16 on first MFMA)
  auto qk = [&](const u16* Kb, f32x16 (&sO)[2]) {
    __builtin_amdgcn_s_setprio(1);
#pragma unroll
    for (int j = 0; j < 2; ++j) {
      const int row = j * 32 + l31;
      v8s k0 = *reinterpret_cast<const v8s*>(
          Kb + (size_t)(row * 8 + ((0 + lh) ^ (row & 7))) * 8);
      sO[j] = __builtin_amdgcn_mfma_f32_32x32x16_bf16(k0, qf[0], z16, 0, 0, 0);
#pragma unroll
      for (int ks = 1; ks < 4; ++ks) {
        v8s kf = *reinterpret_cast<const v8s*>(
            Kb + (size_t)(row * 8 + ((ks * 2 + lh) ^ (row & 7))) * 8);
        sO[j] = __builtin_amdgcn_mfma_f32_32x32x16_bf16(kf, qf[ks], sO[j], 0, 0, 0);
      }
    }
    __builtin_amdgcn_s_setprio(0);
  };

  // one tile's softmax + PV from sacc (scores) and V buffer
  auto halfTile = [&](const u16* Vb, f32x16 (&sIn)[2]) {
    v8s vf[2][4];
#pragma unroll
    for (int n = 0; n < 2; ++n) {
      const int row = n * 32 + l31;
#pragma unroll
      for (int ks = 0; ks < 4; ++ks)
        vf[n][ks] = *reinterpret_cast<const v8s*>(
            Vb + (size_t)(row * 8 + ((ks * 2 + lh) ^ (row & 7))) * 8);
    }

    v8s pf[4];
#pragma unroll
    for (int jj = 0; jj < 2; ++jj) {
      float p[16];
#pragma unroll
      for (int r = 0; r < 16; ++r) p[r] = fexp2(sIn[jj][r]);
      lsum += ((p[0] + p[1]) + (p[2] + p[3])) + ((p[4] + p[5]) + (p[6] + p[7])) +
              (((p[8] + p[9]) + (p[10] + p[11])) + ((p[12] + p[13]) + (p[14] + p[15])));
      u32 X1, X2, X3, X4, Y1, Y2, Y3, Y4;
      asm("v_cvt_pk_bf16_f32 %0, %1, %2" : "=v"(X1) : "v"(p[0]), "v"(p[1]));
      asm("v_cvt_pk_bf16_f32 %0, %1, %2" : "=v"(Y1) : "v"(p[4]), "v"(p[5]));
      asm("v_cvt_pk_bf16_f32 %0, %1, %2" : "=v"(X2) : "v"(p[2]), "v"(p[3]));
      asm("v_cvt_pk_bf16_f32 %0, %1, %2" : "=v"(Y2) : "v"(p[6]), "v"(p[7]));
      asm("v_cvt_pk_bf16_f32 %0, %1, %2" : "=v"(X3) : "v"(p[8]), "v"(p[9]));
      asm("v_cvt_pk_bf16_f32 %0, %1, %2" : "=v"(Y3) : "v"(p[12]), "v"(p[13]));
      asm("v_cvt_pk_bf16_f32 %0, %1, %2" : "=v"(X4) : "v"(p[10]), "v"(p[11]));
      asm("v_cvt_pk_bf16_f32 %0, %1, %2" : "=v"(Y4) : "v"(p[14]), "v"(p[15]));
      asm("v_permlane32_swap_b32 %0, %1" : "+v"(X1), "+v"(Y1));
      asm("v_permlane32_swap_b32 %0, %1" : "+v"(X2), "+v"(Y2));
      asm("v_permlane32_swap_b32 %0, %1" : "+v"(X3), "+v"(Y3));
      asm("v_permlane32_swap_b32 %0, %1" : "+v"(X4), "+v"(Y4));
      uint4 w0; w0.x = X1; w0.y = X2; w0.z = Y1; w0.w = Y2;
      uint4 w1; w1.x = X3; w1.y = X4; w1.z = Y3; w1.w = Y4;
      pf[jj * 2 + 0] = *reinterpret_cast<const v8s*>(&w0);
      pf[jj * 2 + 1] = *reinterpret_cast<const v8s*>(&w1);
    }

    __builtin_amdgcn_s_setprio(1);
#pragma unroll
    for (int ks = 0; ks < 4; ++ks) {
      oacc[0] = __builtin_amdgcn_mfma_f32_32x32x16_bf16(pf[ks], vf[0][ks], oacc[0], 0, 0, 0);
      oacc[1] = __builtin_amdgcn_mfma_f32_32x32x16_bf16(pf[ks], vf[1][ks], oacc[1], 0, 0, 0);
    }
    __builtin_amdgcn_s_setprio(0);
  };

  f32x16 sacc0[2], sacc1[2];

  // body2(t): [vmcnt(0)+barrier]; stage(t+2 -> b2, t+3 -> b3);
  // qk(t from b0)->sacc0; qk(t+1 from b1)->sacc1; half(t); half(t+1)
  auto body2 = [&](int t, int b0, int b1, int b2, int b3, bool doStage) {
    asm volatile("s_waitcnt vmcnt(0)\n\ts_barrier" ::: "memory");
    if (doStage) { stageKV(b2, t + 2); stageKV(b3, t + 3); }
    qk(&Ks[b0][0], sacc0);
    qk(&Ks[b1][0], sacc1);
    halfTile(&Vs[b0][0], sacc0);
    halfTile(&Vs[b1][0], sacc1);
  };

  // prologue: stage tiles 0,1
  stageKV(0, 0);
  stageKV(1, 1);

  for (int tt = 0; tt < 60; tt += 4) {
    body2(tt, 0, 1, 2, 3, true);
    body2(tt + 2, 2, 3, 0, 1, true);
  }
  body2(60, 0, 1, 2, 3, true);    // stages 62,63
  body2(62, 2, 3, 0, 1, false);   // last pair, no staging

  // combine the two kv-halves of the denominator: a+b after swap =
  // lsum(own) + lsum(partner lane^32) in every lane
  u32 ua = __float_as_uint(lsum), ub = ua;
  asm("v_permlane32_swap_b32 %0, %1" : "+v"(ua), "+v"(ub));
  const float lf = __uint_as_float(ua) + __uint_as_float(ub);

  // finalize: rows of oacc are q = (r&3) + 8*(r>>2) + 4*lh (+q0); l at lane=q
#pragma unroll
  for (int r = 0; r < 16; ++r) {
    const int crow = (r & 3) + 8 * (r >> 2) + 4 * lh;
    const float inv = __builtin_amdgcn_rcpf(__shfl(lf, crow));
    const int q = q0 + crow;
    const size_t base = (size_t)q * DM + h * HDIM + l31;
    Aout[base] = f2bs(oacc[0][r] * inv);
    Aout[base + 32] = f2bs(oacc[1][r] * inv);
  }
}

// ---- launcher ----------------------------------------------------------
extern "C" void kernel_launch(void* const* d_in, const int* in_sizes, int n_in,
                              void* d_out, int out_size, void* d_ws, size_t ws_size,
                              hipStream_t stream) {
  const float* x  = (const float*)d_in[0];
  const float* wq = (const float*)d_in[1];
  const float* bq = (const float*)d_in[2];
  const float* wk = (const float*)d_in[3];
  const float* bk = (const float*)d_in[4];
  const float* wv = (const float*)d_in[5];
  const float* bv = (const float*)d_in[6];
  const float* wo = (const float*)d_in[7];
  const float* bo = (const float*)d_in[8];
  float* out = (float*)d_out;

  char* ws = (char*)d_ws;
  u16* xb  = (u16*)(ws);                          // [4096][1024] bf16, 8MB
  u16* wqT = (u16*)(ws + (8u << 20));             // [1024][1024] bf16, 2MB each
  u16* wkT = wqT + 1024 * 1024;
  u16* wvT = wkT + 1024 * 1024;
  u16* woT = wvT + 1024 * 1024;
  u16* Qh  = (u16*)(ws + (16u << 20));            // [16][4096][64] bf16, 8MB
  u16* Kh  = Qh + 16 * 4096 * 64;
  u16* Vth = Kh + 16 * 4096 * 64;                 // [16][64][4096]
  u16* Ao  = Vth + 16 * 4096 * 64;                // [4096][1024]

  dim3 pg(32, 32, 6);
  k_prep<<<pg, 256, 0, stream>>>(x, wq, wk, wv, wo, xb, wqT, wkT, wvT, woT);
  dim3 gg(32, 8, 3);
  k_gemm_qkv<<<gg, 256, 0, stream>>>(xb, wqT, wkT, wvT, bq, bk, bv, Qh, Kh, Vth);
  k_attn<<<512, 256, 0, stream>>>(Qh, Kh, Vth, Ao);
  dim3 og(32, 16);
  k_gemm_o<<<og, 256, 0, stream>>>(Ao, woT, bo, out);
}

// Round 11
// 151.659 us; speedup vs baseline: 5.9037x; 1.0106x over previous
//
#include <hip/hip_runtime.h>

typedef unsigned short u16;
typedef unsigned int u32;
typedef short v8s __attribute__((ext_vector_type(8)));
typedef float f32x4 __attribute__((ext_vector_type(4)));
typedef float f32x16 __attribute__((ext_vector_type(16)));

#define S_LEN 4096
#define DM 1024
#define HDIM 64
#define CEXP 0.18033688f /* 0.125 * log2(e), folded into Q at GEMM epilogue */

// ---- helpers ----------------------------------------------------------
__device__ __forceinline__ u16 f2bs(float f) {
  u32 u = __float_as_uint(f);
  u32 r = 0x7FFFu + ((u >> 16) & 1u);
  return (u16)((u + r) >> 16);
}

__device__ __forceinline__ float fexp2(float x) {
  float r;
  asm("v_exp_f32 %0, %1" : "=v"(r) : "v"(x));   // raw 2^x, args bounded
  return r;
}

__device__ __forceinline__ void gstage16(const void* g, void* lds_wave_base) {
  __builtin_amdgcn_global_load_lds(
      (const __attribute__((address_space(1))) u32*)g,
      (__attribute__((address_space(3))) u32*)lds_wave_base, 16, 0, 0);
}

__device__ __forceinline__ f32x16 vzero16() {
  f32x16 v;
#pragma unroll
  for (int r = 0; r < 16; ++r) v[r] = 0.f;
  return v;
}

// ---- fused prep: 4x weight transpose+cvt, plus x fp32->bf16 ------------
// grid (32,32,6): z<4 -> wtrans w[z]; z in {4,5} -> cvt slice
__global__ __launch_bounds__(256) void k_prep(
    const float* __restrict__ x,
    const float* __restrict__ w0, const float* __restrict__ w1,
    const float* __restrict__ w2, const float* __restrict__ w3,
    u16* __restrict__ xb,
    u16* __restrict__ t0, u16* __restrict__ t1,
    u16* __restrict__ t2, u16* __restrict__ t3) {
  const int z = blockIdx.z;
  if (z < 4) {
    __shared__ float tile[32][33];
    const float* w; u16* wt;
    switch (z) {
      case 0: w = w0; wt = t0; break;
      case 1: w = w1; wt = t1; break;
      case 2: w = w2; wt = t2; break;
      default: w = w3; wt = t3; break;
    }
    const int r = threadIdx.x >> 3;
    const int c4 = (threadIdx.x & 7) * 4;
    const int k0 = blockIdx.x * 32, n0 = blockIdx.y * 32;
    float4 v = *reinterpret_cast<const float4*>(w + (size_t)(k0 + r) * DM + n0 + c4);
    tile[r][c4] = v.x; tile[r][c4 + 1] = v.y; tile[r][c4 + 2] = v.z; tile[r][c4 + 3] = v.w;
    __syncthreads();
    u16 o4[4] = {f2bs(tile[c4][r]), f2bs(tile[c4 + 1][r]),
                 f2bs(tile[c4 + 2][r]), f2bs(tile[c4 + 3][r])};
    *reinterpret_cast<uint2*>(wt + (size_t)(n0 + r) * DM + k0 + c4) =
        *reinterpret_cast<const uint2*>(o4);
  } else {
    const int ci = ((z - 4) * 1024 + blockIdx.y * 32 + blockIdx.x) * 256 + threadIdx.x;
    const float4* p = reinterpret_cast<const float4*>(x) + (size_t)ci * 2;
    float4 a = p[0], b = p[1];
    u16 t[8] = {f2bs(a.x), f2bs(a.y), f2bs(a.z), f2bs(a.w),
                f2bs(b.x), f2bs(b.y), f2bs(b.z), f2bs(b.w)};
    reinterpret_cast<uint4*>(xb)[ci] = *reinterpret_cast<const uint4*>(t);
  }
}

// ---- GEMM core (128x128, BK=64): C = A[M,K] @ Bt[N,K]^T + bias ---------
// BK=64 halves barrier count vs BK=32 (the m97-structure barrier-drain
// stall); frags read per 32-K sub-step so transient regs stay at 8 v8s.
// Staging: 1024 slots/operand of 16B; slot s -> row=s>>3, chunk=(s&7)^(row&7)
template <int MODE>
__device__ __forceinline__ void gemm_core(
    u16* __restrict__ As, u16* __restrict__ Bs,
    const u16* __restrict__ A, const u16* __restrict__ Bt,
    const float* __restrict__ bias, void* __restrict__ Cout, float oscale) {
  constexpr int K = DM;
  const int tid = threadIdx.x;
  const int lane = tid & 63, wave = tid >> 6;
  const int wm = wave >> 1, wn = wave & 1;
  const int l15 = lane & 15, l4 = lane >> 4;
  const int bm0 = blockIdx.x * 128, bn0 = blockIdx.y * 128;

  f32x4 acc[4][4];
#pragma unroll
  for (int m = 0; m < 4; ++m)
#pragma unroll
    for (int n = 0; n < 4; ++n) acc[m][n] = 0.f;

  int ra[4], ca[4];
#pragma unroll
  for (int i = 0; i < 4; ++i) {
    const int s = i * 256 + tid;
    ra[i] = s >> 3;
    ca[i] = ((s & 7) ^ (ra[i] & 7)) * 8;
  }
  const u16* Ab = A + (size_t)bm0 * K;
  const u16* Bb = Bt + (size_t)bn0 * K;

  for (int k0 = 0; k0 < K; k0 += 64) {
#pragma unroll
    for (int i = 0; i < 4; ++i) {
      gstage16(Ab + (size_t)ra[i] * K + k0 + ca[i], As + (size_t)(i * 256 + wave * 64) * 8);
      gstage16(Bb + (size_t)ra[i] * K + k0 + ca[i], Bs + (size_t)(i * 256 + wave * 64) * 8);
    }
    __syncthreads();
#pragma unroll
    for (int s = 0; s < 2; ++s) {
      v8s af[4], bfr[4];
#pragma unroll
      for (int m = 0; m < 4; ++m) {
        const int rowa = wm * 64 + m * 16 + l15;
        af[m] = *reinterpret_cast<const v8s*>(
            As + (size_t)(rowa * 8 + ((s * 4 + l4) ^ (rowa & 7))) * 8);
        const int rowb = wn * 64 + m * 16 + l15;
        bfr[m] = *reinterpret_cast<const v8s*>(
            Bs + (size_t)(rowb * 8 + ((s * 4 + l4) ^ (rowb & 7))) * 8);
      }
#pragma unroll
      for (int m = 0; m < 4; ++m)
#pragma unroll
        for (int n = 0; n < 4; ++n)
          acc[m][n] = __builtin_amdgcn_mfma_f32_16x16x32_bf16(af[m], bfr[n], acc[m][n], 0, 0, 0);
    }
    __syncthreads();
  }

#pragma unroll
  for (int m = 0; m < 4; ++m) {
    const int gs0 = bm0 + wm * 64 + m * 16 + l4 * 4;
#pragma unroll
    for (int n = 0; n < 4; ++n) {
      const int gn = bn0 + wn * 64 + n * 16 + l15;
      const float bv = bias[gn];
      if (MODE == 0) {
        u16* O = (u16*)Cout;
        const size_t base = (size_t)(gn >> 6) * (S_LEN * HDIM) + (size_t)(gn & 63);
#pragma unroll
        for (int r = 0; r < 4; ++r)
          O[base + (size_t)(gs0 + r) * HDIM] = f2bs((acc[m][n][r] + bv) * oscale);
      } else {
        u16* O = (u16*)Cout;
        u16 p4[4];
#pragma unroll
        for (int r = 0; r < 4; ++r) p4[r] = f2bs(acc[m][n][r] + bv);
        *reinterpret_cast<uint2*>(O + (size_t)(gn >> 6) * (HDIM * S_LEN) +
                                  (size_t)(gn & 63) * S_LEN + gs0) =
            *reinterpret_cast<const uint2*>(p4);
      }
    }
  }
}

__global__ __launch_bounds__(256) void k_gemm_qkv(
    const u16* __restrict__ A,
    const u16* __restrict__ wq, const u16* __restrict__ wk, const u16* __restrict__ wv,
    const float* __restrict__ bq, const float* __restrict__ bk, const float* __restrict__ bv,
    u16* __restrict__ Qo, u16* __restrict__ Ko, u16* __restrict__ Vo) {
  __shared__ __attribute__((aligned(16))) u16 As[128 * 64];
  __shared__ __attribute__((aligned(16))) u16 Bs[128 * 64];
  const int z = blockIdx.z;
  if (z == 0)      gemm_core<0>(As, Bs, A, wq, bq, Qo, CEXP);
  else if (z == 1) gemm_core<0>(As, Bs, A, wk, bk, Ko, 1.f);
  else             gemm_core<1>(As, Bs, A, wv, bv, Vo, 1.f);
}

// ---- output GEMM, 128x64 tiles: grid (32,16) = 512 blocks = 2/CU -------
__global__ __launch_bounds__(256) void k_gemm_o(
    const u16* __restrict__ A, const u16* __restrict__ wo,
    const float* __restrict__ bo, float* __restrict__ out) {
  __shared__ __attribute__((aligned(16))) u16 As[128 * 32];
  __shared__ __attribute__((aligned(16))) u16 Bs[64 * 32];
  constexpr int K = DM, N = DM;
  const int tid = threadIdx.x;
  const int lane = tid & 63, wave = tid >> 6;
  const int wm = wave >> 1, wn = wave & 1;
  const int l15 = lane & 15, l4 = lane >> 4;
  const int bm0 = blockIdx.x * 128, bn0 = blockIdx.y * 64;

  f32x4 acc[4][2];
#pragma unroll
  for (int m = 0; m < 4; ++m)
#pragma unroll
    for (int n = 0; n < 2; ++n) acc[m][n] = 0.f;

  const int s0 = tid, s1 = tid + 256;
  const int ra0 = s0 >> 2, ca0 = ((s0 & 3) ^ ((ra0 >> 1) & 3)) * 8;
  const int ra1 = s1 >> 2, ca1 = ((s1 & 3) ^ ((ra1 >> 1) & 3)) * 8;
  const int rb = tid >> 2,  cb = ((tid & 3) ^ ((rb >> 1) & 3)) * 8;
  const u16* Ab = A + (size_t)bm0 * K;
  const u16* Bb = wo + (size_t)bn0 * K;
  u16* ldsA0 = As + (size_t)(wave * 64) * 8;
  u16* ldsA1 = As + (size_t)(256 + wave * 64) * 8;
  u16* ldsB0 = Bs + (size_t)(wave * 64) * 8;

  for (int k0 = 0; k0 < K; k0 += 32) {
    gstage16(Ab + (size_t)ra0 * K + k0 + ca0, ldsA0);
    gstage16(Ab + (size_t)ra1 * K + k0 + ca1, ldsA1);
    gstage16(Bb + (size_t)rb * K + k0 + cb, ldsB0);
    __syncthreads();
    v8s af[4], bfr[2];
#pragma unroll
    for (int m = 0; m < 4; ++m) {
      const int rowa = wm * 64 + m * 16 + l15;
      af[m] = *reinterpret_cast<const v8s*>(
          As + (size_t)(rowa * 4 + (l4 ^ ((rowa >> 1) & 3))) * 8);
    }
#pragma unroll
    for (int n = 0; n < 2; ++n) {
      const int rowb = wn * 32 + n * 16 + l15;
      bfr[n] = *reinterpret_cast<const v8s*>(
          Bs + (size_t)(rowb * 4 + (l4 ^ ((rowb >> 1) & 3))) * 8);
    }
#pragma unroll
    for (int m = 0; m < 4; ++m)
#pragma unroll
      for (int n = 0; n < 2; ++n)
        acc[m][n] = __builtin_amdgcn_mfma_f32_16x16x32_bf16(af[m], bfr[n], acc[m][n], 0, 0, 0);
    __syncthreads();
  }

#pragma unroll
  for (int m = 0; m < 4; ++m) {
    const int gs0 = bm0 + wm * 64 + m * 16 + l4 * 4;
#pragma unroll
    for (int n = 0; n < 2; ++n) {
      const int gn = bn0 + wn * 32 + n * 16 + l15;
      const float bv = bo[gn];
#pragma unroll
      for (int r = 0; r < 4; ++r)
        out[(size_t)(gs0 + r) * N + gn] = acc[m][n][r] + bv;
    }
  }
}

// ---- flash attention: Q,K [H][S][64] (Q pre-scaled by CEXP), Vt [H][64][S]
// -> Aout bf16 [S][DM].
// 4-buffer K/V ring, ONE barrier per TWO tiles. Pipeline per body2:
// qk(t), qk(t+1), pack(t), pack(t+1), pv(t), pv(t+1) — both softmax packs
// run between the QK and PV MFMA clusters (hides cvt/permlane latency,
// consolidates 16 PV MFMAs into one matrix-pipe run).
__global__ __launch_bounds__(256, 2) void k_attn(
    const u16* __restrict__ Q, const u16* __restrict__ Kg,
    const u16* __restrict__ Vt, u16* __restrict__ Aout) {
  __shared__ __attribute__((aligned(16))) u16 Ks[4][64 * 64];
  __shared__ __attribute__((aligned(16))) u16 Vs[4][64 * 64];

  const int tid = threadIdx.x;
  const int lane = tid & 63, wave = tid >> 6;
  const int l31 = lane & 31, lh = lane >> 5;

  // XCD-aware remap: 2 heads per XCD (K/V ~2MB fits one L2)
  const int id = blockIdx.x;
  const int xcd = id & 7, sp = id >> 3;
  const int h = xcd * 2 + (sp & 1);
  const int qb = sp >> 1;
  const int q0 = qb * 128 + wave * 32;

  const u16* Qh = Q + (size_t)h * S_LEN * HDIM;
  const u16* Kh = Kg + (size_t)h * S_LEN * HDIM;
  const u16* Vh = Vt + (size_t)h * HDIM * S_LEN;

  // Q B-frags: col q = l31, k = ks*16 + lh*8 + e
  v8s qf[4];
#pragma unroll
  for (int ks = 0; ks < 4; ++ks)
    qf[ks] = *reinterpret_cast<const v8s*>(
        Qh + (size_t)(q0 + l31) * HDIM + ks * 16 + lh * 8);

  const f32x16 z16 = vzero16();
  f32x16 oacc[2];
  oacc[0] = z16; oacc[1] = z16;
  float lsum = 0.f;   // denominator partial: q = l31, kv-half = lh

  // staging map: tile [64 rows][8 chunks of 16B], chunk ^= row&7
  const int s0i = tid, s1i = tid + 256;
  const int r0 = s0i >> 3, c0 = ((s0i & 7) ^ (r0 & 7)) * 8;
  const int r1 = s1i >> 3, c1 = ((s1i & 7) ^ (r1 & 7)) * 8;

  auto stageKV = [&](int b, int t) {
    const int kv0 = t * 64;
    gstage16(Kh + (size_t)(kv0 + r0) * HDIM + c0, &Ks[b][(wave * 64) * 8]);
    gstage16(Kh + (size_t)(kv0 + r1) * HDIM + c1, &Ks[b][(256 + wave * 64) * 8]);
    gstage16(Vh + (size_t)r0 * S_LEN + kv0 + c0, &Vs[b][(wave * 64) * 8]);
    gstage16(Vh + (size_t)r1 * S_LEN + kv0 + c1, &Vs[b][(256 + wave * 64) * 8]);
  };

  // QK into sO from K LDS buffer (C = z16 on first MFMA)
  auto qk = [&](const u16* Kb, f32x16 (&sO)[2]) {
    __builtin_amdgcn_s_setprio(1);
#pragma unroll
    for (int j = 0; j < 2; ++j) {
      const int row = j * 32 + l31;
      v8s k0 = *reinterpret_cast<const v8s*>(
          Kb + (size_t)(row * 8 + ((0 + lh) ^ (row & 7))) * 8);
      sO[j] = __builtin_amdgcn_mfma_f32_32x32x16_bf16(k0, qf[0], z16, 0, 0, 0);
#pragma unroll
      for (int ks = 1; ks < 4; ++ks) {
        v8s kf = *reinterpret_cast<const v8s*>(
            Kb + (size_t)(row * 8 + ((ks * 2 + lh) ^ (row & 7))) * 8);
        sO[j] = __builtin_amdgcn_mfma_f32_32x32x16_bf16(kf, qf[ks], sO[j], 0, 0, 0);
      }
    }
    __builtin_amdgcn_s_setprio(0);
  };

  // softmax pack: scores -> bf16 PV A-frags (pure VALU/trans, in-register)
  auto pack = [&](f32x16 (&sIn)[2], v8s (&pf)[4]) {
#pragma unroll
    for (int jj = 0; jj < 2; ++jj) {
      float p[16];
#pragma unroll
      for (int r = 0; r < 16; ++r) p[r] = fexp2(sIn[jj][r]);
      lsum += ((p[0] + p[1]) + (p[2] + p[3])) + ((p[4] + p[5]) + (p[6] + p[7])) +
              (((p[8] + p[9]) + (p[10] + p[11])) + ((p[12] + p[13]) + (p[14] + p[15])));
      u32 X1, X2, X3, X4, Y1, Y2, Y3, Y4;
      asm("v_cvt_pk_bf16_f32 %0, %1, %2" : "=v"(X1) : "v"(p[0]), "v"(p[1]));
      asm("v_cvt_pk_bf16_f32 %0, %1, %2" : "=v"(Y1) : "v"(p[4]), "v"(p[5]));
      asm("v_cvt_pk_bf16_f32 %0, %1, %2" : "=v"(X2) : "v"(p[2]), "v"(p[3]));
      asm("v_cvt_pk_bf16_f32 %0, %1, %2" : "=v"(Y2) : "v"(p[6]), "v"(p[7]));
      asm("v_cvt_pk_bf16_f32 %0, %1, %2" : "=v"(X3) : "v"(p[8]), "v"(p[9]));
      asm("v_cvt_pk_bf16_f32 %0, %1, %2" : "=v"(Y3) : "v"(p[12]), "v"(p[13]));
      asm("v_cvt_pk_bf16_f32 %0, %1, %2" : "=v"(X4) : "v"(p[10]), "v"(p[11]));
      asm("v_cvt_pk_bf16_f32 %0, %1, %2" : "=v"(Y4) : "v"(p[14]), "v"(p[15]));
      asm("v_permlane32_swap_b32 %0, %1" : "+v"(X1), "+v"(Y1));
      asm("v_permlane32_swap_b32 %0, %1" : "+v"(X2), "+v"(Y2));
      asm("v_permlane32_swap_b32 %0, %1" : "+v"(X3), "+v"(Y3));
      asm("v_permlane32_swap_b32 %0, %1" : "+v"(X4), "+v"(Y4));
      uint4 w0; w0.x = X1; w0.y = X2; w0.z = Y1; w0.w = Y2;
      uint4 w1; w1.x = X3; w1.y = X4; w1.z = Y3; w1.w = Y4;
      pf[jj * 2 + 0] = *reinterpret_cast<const v8s*>(&w0);
      pf[jj * 2 + 1] = *reinterpret_cast<const v8s*>(&w1);
    }
  };

  // PV: O[q][hd] += P @ V (vf ds_reads + 8 MFMA, no VALU)
  auto pv = [&](const u16* Vb, v8s (&pf)[4]) {
    v8s vf[2][4];
#pragma unroll
    for (int n = 0; n < 2; ++n) {
      const int row = n * 32 + l31;
#pragma unroll
      for (int ks = 0; ks < 4; ++ks)
        vf[n][ks] = *reinterpret_cast<const v8s*>(
            Vb + (size_t)(row * 8 + ((ks * 2 + lh) ^ (row & 7))) * 8);
    }
    __builtin_amdgcn_s_setprio(1);
#pragma unroll
    for (int ks = 0; ks < 4; ++ks) {
      oacc[0] = __builtin_amdgcn_mfma_f32_32x32x16_bf16(pf[ks], vf[0][ks], oacc[0], 0, 0, 0);
      oacc[1] = __builtin_amdgcn_mfma_f32_32x32x16_bf16(pf[ks], vf[1][ks], oacc[1], 0, 0, 0);
    }
    __builtin_amdgcn_s_setprio(0);
  };

  f32x16 sacc0[2], sacc1[2];

  // body2(t): [vmcnt(0)+barrier]; stage(t+2,t+3); qk,qk; pack,pack; pv,pv
  auto body2 = [&](int t, int b0, int b1, int b2, int b3, bool doStage) {
    asm volatile("s_waitcnt vmcnt(0)\n\ts_barrier" ::: "memory");
    if (doStage) { stageKV(b2, t + 2); stageKV(b3, t + 3); }
    qk(&Ks[b0][0], sacc0);
    qk(&Ks[b1][0], sacc1);
    v8s pf0[4], pf1[4];
    pack(sacc0, pf0);
    pack(sacc1, pf1);
    pv(&Vs[b0][0], pf0);
    pv(&Vs[b1][0], pf1);
  };

  // prologue: stage tiles 0,1
  stageKV(0, 0);
  stageKV(1, 1);

  for (int tt = 0; tt < 60; tt += 4) {
    body2(tt, 0, 1, 2, 3, true);
    body2(tt + 2, 2, 3, 0, 1, true);
  }
  body2(60, 0, 1, 2, 3, true);    // stages 62,63
  body2(62, 2, 3, 0, 1, false);   // last pair, no staging

  // combine the two kv-halves of the denominator: a+b after swap =
  // lsum(own) + lsum(partner lane^32) in every lane
  u32 ua = __float_as_uint(lsum), ub = ua;
  asm("v_permlane32_swap_b32 %0, %1" : "+v"(ua), "+v"(ub));
  const float lf = __uint_as_float(ua) + __uint_as_float(ub);

  // finalize: rows of oacc are q = (r&3) + 8*(r>>2) + 4*lh (+q0); l at lane=q
#pragma unroll
  for (int r = 0; r < 16; ++r) {
    const int crow = (r & 3) + 8 * (r >> 2) + 4 * lh;
    const float inv = __builtin_amdgcn_rcpf(__shfl(lf, crow));
    const int q = q0 + crow;
    const size_t base = (size_t)q * DM + h * HDIM + l31;
    Aout[base] = f2bs(oacc[0][r] * inv);
    Aout[base + 32] = f2bs(oacc[1][r] * inv);
  }
}

// ---- launcher ----------------------------------------------------------
extern "C" void kernel_launch(void* const* d_in, const int* in_sizes, int n_in,
                              void* d_out, int out_size, void* d_ws, size_t ws_size,
                              hipStream_t stream) {
  const float* x  = (const float*)d_in[0];
  const float* wq = (const float*)d_in[1];
  const float* bq = (const float*)d_in[2];
  const float* wk = (const float*)d_in[3];
  const float* bk = (const float*)d_in[4];
  const float* wv = (const float*)d_in[5];
  const float* bv = (const float*)d_in[6];
  const float* wo = (const float*)d_in[7];
  const float* bo = (const float*)d_in[8];
  float* out = (float*)d_out;

  char* ws = (char*)d_ws;
  u16* xb  = (u16*)(ws);                          // [4096][1024] bf16, 8MB
  u16* wqT = (u16*)(ws + (8u << 20));             // [1024][1024] bf16, 2MB each
  u16* wkT = wqT + 1024 * 1024;
  u16* wvT = wkT + 1024 * 1024;
  u16* woT = wvT + 1024 * 1024;
  u16* Qh  = (u16*)(ws + (16u << 20));            // [16][4096][64] bf16, 8MB
  u16* Kh  = Qh + 16 * 4096 * 64;
  u16* Vth = Kh + 16 * 4096 * 64;                 // [16][64][4096]
  u16* Ao  = Vth + 16 * 4096 * 64;                // [4096][1024]

  dim3 pg(32, 32, 6);
  k_prep<<<pg, 256, 0, stream>>>(x, wq, wk, wv, wo, xb, wqT, wkT, wvT, woT);
  dim3 gg(32, 8, 3);
  k_gemm_qkv<<<gg, 256, 0, stream>>>(xb, wqT, wkT, wvT, bq, bk, bv, Qh, Kh, Vth);
  k_attn<<<512, 256, 0, stream>>>(Qh, Kh, Vth, Ao);
  dim3 og(32, 16);
  k_gemm_o<<<og, 256, 0, stream>>>(Ao, woT, bo, out);
}

// Round 12
// 147.856 us; speedup vs baseline: 6.0556x; 1.0257x over previous
//
#include <hip/hip_runtime.h>

typedef unsigned short u16;
typedef unsigned int u32;
typedef short v8s __attribute__((ext_vector_type(8)));
typedef float f32x4 __attribute__((ext_vector_type(4)));
typedef float f32x16 __attribute__((ext_vector_type(16)));

#define S_LEN 4096
#define DM 1024
#define HDIM 64
#define CEXP 0.18033688f /* 0.125 * log2(e), folded into Q at GEMM epilogue */

// ---- helpers ----------------------------------------------------------
__device__ __forceinline__ u16 f2bs(float f) {
  u32 u = __float_as_uint(f);
  u32 r = 0x7FFFu + ((u >> 16) & 1u);
  return (u16)((u + r) >> 16);
}

__device__ __forceinline__ float fexp2(float x) {
  float r;
  asm("v_exp_f32 %0, %1" : "=v"(r) : "v"(x));   // raw 2^x, args bounded
  return r;
}

__device__ __forceinline__ void gstage16(const void* g, void* lds_wave_base) {
  __builtin_amdgcn_global_load_lds(
      (const __attribute__((address_space(1))) u32*)g,
      (__attribute__((address_space(3))) u32*)lds_wave_base, 16, 0, 0);
}

__device__ __forceinline__ f32x16 vzero16() {
  f32x16 v;
#pragma unroll
  for (int r = 0; r < 16; ++r) v[r] = 0.f;
  return v;
}

// ---- fused prep: 4x weight transpose+cvt (64x64 tiles) + x fp32->bf16 --
// grid (16,16,5): z<4 -> wtrans w[z]; z==4 -> cvt (grid-strided, 8/thread)
__global__ __launch_bounds__(256) void k_prep(
    const float* __restrict__ x,
    const float* __restrict__ w0, const float* __restrict__ w1,
    const float* __restrict__ w2, const float* __restrict__ w3,
    u16* __restrict__ xb,
    u16* __restrict__ t0, u16* __restrict__ t1,
    u16* __restrict__ t2, u16* __restrict__ t3) {
  const int z = blockIdx.z;
  if (z < 4) {
    __shared__ float tile[64][65];
    const float* w; u16* wt;
    switch (z) {
      case 0: w = w0; wt = t0; break;
      case 1: w = w1; wt = t1; break;
      case 2: w = w2; wt = t2; break;
      default: w = w3; wt = t3; break;
    }
    const int r = threadIdx.x >> 4;          // 0..15
    const int c4 = (threadIdx.x & 15) * 4;   // 0..60
    const int k0 = blockIdx.x * 64, n0 = blockIdx.y * 64;
#pragma unroll
    for (int i = 0; i < 4; ++i) {
      const int row = r + i * 16;
      float4 v = *reinterpret_cast<const float4*>(w + (size_t)(k0 + row) * DM + n0 + c4);
      tile[row][c4] = v.x; tile[row][c4 + 1] = v.y;
      tile[row][c4 + 2] = v.z; tile[row][c4 + 3] = v.w;
    }
    __syncthreads();
#pragma unroll
    for (int i = 0; i < 4; ++i) {
      const int row = r + i * 16;            // output n-row
      u16 o4[4] = {f2bs(tile[c4][row]), f2bs(tile[c4 + 1][row]),
                   f2bs(tile[c4 + 2][row]), f2bs(tile[c4 + 3][row])};
      *reinterpret_cast<uint2*>(wt + (size_t)(n0 + row) * DM + k0 + c4) =
          *reinterpret_cast<const uint2*>(o4);
    }
  } else {
    // cvt: 256 blocks x 256 threads x 8 uint4 = 524288 uint4 (4M floats)
    const int bid = blockIdx.y * 16 + blockIdx.x;
#pragma unroll
    for (int j = 0; j < 8; ++j) {
      const int ci = j * 65536 + bid * 256 + threadIdx.x;
      const float4* p = reinterpret_cast<const float4*>(x) + (size_t)ci * 2;
      float4 a = p[0], b = p[1];
      u16 t[8] = {f2bs(a.x), f2bs(a.y), f2bs(a.z), f2bs(a.w),
                  f2bs(b.x), f2bs(b.y), f2bs(b.z), f2bs(b.w)};
      reinterpret_cast<uint4*>(xb)[ci] = *reinterpret_cast<const uint4*>(t);
    }
  }
}

// ---- GEMM core (128x128, BK=64): C = A[M,K] @ Bt[N,K]^T + bias ---------
// Staging: 1024 slots/operand of 16B; slot s -> row=s>>3, chunk=(s&7)^(row&7)
template <int MODE>
__device__ __forceinline__ void gemm_core(
    u16* __restrict__ As, u16* __restrict__ Bs,
    const u16* __restrict__ A, const u16* __restrict__ Bt,
    const float* __restrict__ bias, void* __restrict__ Cout, float oscale) {
  constexpr int K = DM;
  const int tid = threadIdx.x;
  const int lane = tid & 63, wave = tid >> 6;
  const int wm = wave >> 1, wn = wave & 1;
  const int l15 = lane & 15, l4 = lane >> 4;
  const int bm0 = blockIdx.x * 128, bn0 = blockIdx.y * 128;

  f32x4 acc[4][4];
#pragma unroll
  for (int m = 0; m < 4; ++m)
#pragma unroll
    for (int n = 0; n < 4; ++n) acc[m][n] = 0.f;

  int ra[4], ca[4];
#pragma unroll
  for (int i = 0; i < 4; ++i) {
    const int s = i * 256 + tid;
    ra[i] = s >> 3;
    ca[i] = ((s & 7) ^ (ra[i] & 7)) * 8;
  }
  const u16* Ab = A + (size_t)bm0 * K;
  const u16* Bb = Bt + (size_t)bn0 * K;

  for (int k0 = 0; k0 < K; k0 += 64) {
#pragma unroll
    for (int i = 0; i < 4; ++i) {
      gstage16(Ab + (size_t)ra[i] * K + k0 + ca[i], As + (size_t)(i * 256 + wave * 64) * 8);
      gstage16(Bb + (size_t)ra[i] * K + k0 + ca[i], Bs + (size_t)(i * 256 + wave * 64) * 8);
    }
    __syncthreads();
#pragma unroll
    for (int s = 0; s < 2; ++s) {
      v8s af[4], bfr[4];
#pragma unroll
      for (int m = 0; m < 4; ++m) {
        const int rowa = wm * 64 + m * 16 + l15;
        af[m] = *reinterpret_cast<const v8s*>(
            As + (size_t)(rowa * 8 + ((s * 4 + l4) ^ (rowa & 7))) * 8);
        const int rowb = wn * 64 + m * 16 + l15;
        bfr[m] = *reinterpret_cast<const v8s*>(
            Bs + (size_t)(rowb * 8 + ((s * 4 + l4) ^ (rowb & 7))) * 8);
      }
#pragma unroll
      for (int m = 0; m < 4; ++m)
#pragma unroll
        for (int n = 0; n < 4; ++n)
          acc[m][n] = __builtin_amdgcn_mfma_f32_16x16x32_bf16(af[m], bfr[n], acc[m][n], 0, 0, 0);
    }
    __syncthreads();
  }

#pragma unroll
  for (int m = 0; m < 4; ++m) {
    const int gs0 = bm0 + wm * 64 + m * 16 + l4 * 4;
#pragma unroll
    for (int n = 0; n < 4; ++n) {
      const int gn = bn0 + wn * 64 + n * 16 + l15;
      const float bv = bias[gn];
      if (MODE == 0) {
        u16* O = (u16*)Cout;
        const size_t base = (size_t)(gn >> 6) * (S_LEN * HDIM) + (size_t)(gn & 63);
#pragma unroll
        for (int r = 0; r < 4; ++r)
          O[base + (size_t)(gs0 + r) * HDIM] = f2bs((acc[m][n][r] + bv) * oscale);
      } else {
        u16* O = (u16*)Cout;
        u16 p4[4];
#pragma unroll
        for (int r = 0; r < 4; ++r) p4[r] = f2bs(acc[m][n][r] + bv);
        *reinterpret_cast<uint2*>(O + (size_t)(gn >> 6) * (HDIM * S_LEN) +
                                  (size_t)(gn & 63) * S_LEN + gs0) =
            *reinterpret_cast<const uint2*>(p4);
      }
    }
  }
}

__global__ __launch_bounds__(256) void k_gemm_qkv(
    const u16* __restrict__ A,
    const u16* __restrict__ wq, const u16* __restrict__ wk, const u16* __restrict__ wv,
    const float* __restrict__ bq, const float* __restrict__ bk, const float* __restrict__ bv,
    u16* __restrict__ Qo, u16* __restrict__ Ko, u16* __restrict__ Vo) {
  __shared__ __attribute__((aligned(16))) u16 As[128 * 64];
  __shared__ __attribute__((aligned(16))) u16 Bs[128 * 64];
  const int z = blockIdx.z;
  if (z == 0)      gemm_core<0>(As, Bs, A, wq, bq, Qo, CEXP);
  else if (z == 1) gemm_core<0>(As, Bs, A, wk, bk, Ko, 1.f);
  else             gemm_core<1>(As, Bs, A, wv, bv, Vo, 1.f);
}

// ---- output GEMM, 128x64 tiles, BK=64: grid (32,16) = 512 blocks -------
__global__ __launch_bounds__(256) void k_gemm_o(
    const u16* __restrict__ A, const u16* __restrict__ wo,
    const float* __restrict__ bo, float* __restrict__ out) {
  __shared__ __attribute__((aligned(16))) u16 As[128 * 64];
  __shared__ __attribute__((aligned(16))) u16 Bs[64 * 64];
  constexpr int K = DM, N = DM;
  const int tid = threadIdx.x;
  const int lane = tid & 63, wave = tid >> 6;
  const int wm = wave >> 1, wn = wave & 1;
  const int l15 = lane & 15, l4 = lane >> 4;
  const int bm0 = blockIdx.x * 128, bn0 = blockIdx.y * 64;

  f32x4 acc[4][2];
#pragma unroll
  for (int m = 0; m < 4; ++m)
#pragma unroll
    for (int n = 0; n < 2; ++n) acc[m][n] = 0.f;

  int ra[4], ca[4];
#pragma unroll
  for (int i = 0; i < 4; ++i) {
    const int s = i * 256 + tid;
    ra[i] = s >> 3;
    ca[i] = ((s & 7) ^ (ra[i] & 7)) * 8;
  }
  const u16* Ab = A + (size_t)bm0 * K;
  const u16* Bb = wo + (size_t)bn0 * K;

  for (int k0 = 0; k0 < K; k0 += 64) {
#pragma unroll
    for (int i = 0; i < 4; ++i)
      gstage16(Ab + (size_t)ra[i] * K + k0 + ca[i], As + (size_t)(i * 256 + wave * 64) * 8);
#pragma unroll
    for (int i = 0; i < 2; ++i)
      gstage16(Bb + (size_t)ra[i] * K + k0 + ca[i], Bs + (size_t)(i * 256 + wave * 64) * 8);
    __syncthreads();
#pragma unroll
    for (int s = 0; s < 2; ++s) {
      v8s af[4], bfr[2];
#pragma unroll
      for (int m = 0; m < 4; ++m) {
        const int rowa = wm * 64 + m * 16 + l15;
        af[m] = *reinterpret_cast<const v8s*>(
            As + (size_t)(rowa * 8 + ((s * 4 + l4) ^ (rowa & 7))) * 8);
      }
#pragma unroll
      for (int n = 0; n < 2; ++n) {
        const int rowb = wn * 32 + n * 16 + l15;
        bfr[n] = *reinterpret_cast<const v8s*>(
            Bs + (size_t)(rowb * 8 + ((s * 4 + l4) ^ (rowb & 7))) * 8);
      }
#pragma unroll
      for (int m = 0; m < 4; ++m)
#pragma unroll
        for (int n = 0; n < 2; ++n)
          acc[m][n] = __builtin_amdgcn_mfma_f32_16x16x32_bf16(af[m], bfr[n], acc[m][n], 0, 0, 0);
    }
    __syncthreads();
  }

#pragma unroll
  for (int m = 0; m < 4; ++m) {
    const int gs0 = bm0 + wm * 64 + m * 16 + l4 * 4;
#pragma unroll
    for (int n = 0; n < 2; ++n) {
      const int gn = bn0 + wn * 32 + n * 16 + l15;
      const float bv = bo[gn];
#pragma unroll
      for (int r = 0; r < 4; ++r)
        out[(size_t)(gs0 + r) * N + gn] = acc[m][n][r] + bv;
    }
  }
}

// ---- flash attention: Q,K [H][S][64] (Q pre-scaled by CEXP), Vt [H][64][S]
// -> Aout bf16 [S][DM]. (r11 structure — measured plateau of this topology)
__global__ __launch_bounds__(256, 2) void k_attn(
    const u16* __restrict__ Q, const u16* __restrict__ Kg,
    const u16* __restrict__ Vt, u16* __restrict__ Aout) {
  __shared__ __attribute__((aligned(16))) u16 Ks[4][64 * 64];
  __shared__ __attribute__((aligned(16))) u16 Vs[4][64 * 64];

  const int tid = threadIdx.x;
  const int lane = tid & 63, wave = tid >> 6;
  const int l31 = lane & 31, lh = lane >> 5;

  const int id = blockIdx.x;
  const int xcd = id & 7, sp = id >> 3;
  const int h = xcd * 2 + (sp & 1);
  const int qb = sp >> 1;
  const int q0 = qb * 128 + wave * 32;

  const u16* Qh = Q + (size_t)h * S_LEN * HDIM;
  const u16* Kh = Kg + (size_t)h * S_LEN * HDIM;
  const u16* Vh = Vt + (size_t)h * HDIM * S_LEN;

  v8s qf[4];
#pragma unroll
  for (int ks = 0; ks < 4; ++ks)
    qf[ks] = *reinterpret_cast<const v8s*>(
        Qh + (size_t)(q0 + l31) * HDIM + ks * 16 + lh * 8);

  const f32x16 z16 = vzero16();
  f32x16 oacc[2];
  oacc[0] = z16; oacc[1] = z16;
  float lsum = 0.f;

  const int s0i = tid, s1i = tid + 256;
  const int r0 = s0i >> 3, c0 = ((s0i & 7) ^ (r0 & 7)) * 8;
  const int r1 = s1i >> 3, c1 = ((s1i & 7) ^ (r1 & 7)) * 8;

  auto stageKV = [&](int b, int t) {
    const int kv0 = t * 64;
    gstage16(Kh + (size_t)(kv0 + r0) * HDIM + c0, &Ks[b][(wave * 64) * 8]);
    gstage16(Kh + (size_t)(kv0 + r1) * HDIM + c1, &Ks[b][(256 + wave * 64) * 8]);
    gstage16(Vh + (size_t)r0 * S_LEN + kv0 + c0, &Vs[b][(wave * 64) * 8]);
    gstage16(Vh + (size_t)r1 * S_LEN + kv0 + c1, &Vs[b][(256 + wave * 64) * 8]);
  };

  auto qk = [&](const u16* Kb, f32x16 (&sO)[2]) {
    __builtin_amdgcn_s_setprio(1);
#pragma unroll
    for (int j = 0; j < 2; ++j) {
      const int row = j * 32 + l31;
      v8s k0 = *reinterpret_cast<const v8s*>(
          Kb + (size_t)(row * 8 + ((0 + lh) ^ (row & 7))) * 8);
      sO[j] = __builtin_amdgcn_mfma_f32_32x32x16_bf16(k0, qf[0], z16, 0, 0, 0);
#pragma unroll
      for (int ks = 1; ks < 4; ++ks) {
        v8s kf = *reinterpret_cast<const v8s*>(
            Kb + (size_t)(row * 8 + ((ks * 2 + lh) ^ (row & 7))) * 8);
        sO[j] = __builtin_amdgcn_mfma_f32_32x32x16_bf16(kf, qf[ks], sO[j], 0, 0, 0);
      }
    }
    __builtin_amdgcn_s_setprio(0);
  };

  auto pack = [&](f32x16 (&sIn)[2], v8s (&pf)[4]) {
#pragma unroll
    for (int jj = 0; jj < 2; ++jj) {
      float p[16];
#pragma unroll
      for (int r = 0; r < 16; ++r) p[r] = fexp2(sIn[jj][r]);
      lsum += ((p[0] + p[1]) + (p[2] + p[3])) + ((p[4] + p[5]) + (p[6] + p[7])) +
              (((p[8] + p[9]) + (p[10] + p[11])) + ((p[12] + p[13]) + (p[14] + p[15])));
      u32 X1, X2, X3, X4, Y1, Y2, Y3, Y4;
      asm("v_cvt_pk_bf16_f32 %0, %1, %2" : "=v"(X1) : "v"(p[0]), "v"(p[1]));
      asm("v_cvt_pk_bf16_f32 %0, %1, %2" : "=v"(Y1) : "v"(p[4]), "v"(p[5]));
      asm("v_cvt_pk_bf16_f32 %0, %1, %2" : "=v"(X2) : "v"(p[2]), "v"(p[3]));
      asm("v_cvt_pk_bf16_f32 %0, %1, %2" : "=v"(Y2) : "v"(p[6]), "v"(p[7]));
      asm("v_cvt_pk_bf16_f32 %0, %1, %2" : "=v"(X3) : "v"(p[8]), "v"(p[9]));
      asm("v_cvt_pk_bf16_f32 %0, %1, %2" : "=v"(Y3) : "v"(p[12]), "v"(p[13]));
      asm("v_cvt_pk_bf16_f32 %0, %1, %2" : "=v"(X4) : "v"(p[10]), "v"(p[11]));
      asm("v_cvt_pk_bf16_f32 %0, %1, %2" : "=v"(Y4) : "v"(p[14]), "v"(p[15]));
      asm("v_permlane32_swap_b32 %0, %1" : "+v"(X1), "+v"(Y1));
      asm("v_permlane32_swap_b32 %0, %1" : "+v"(X2), "+v"(Y2));
      asm("v_permlane32_swap_b32 %0, %1" : "+v"(X3), "+v"(Y3));
      asm("v_permlane32_swap_b32 %0, %1" : "+v"(X4), "+v"(Y4));
      uint4 w0; w0.x = X1; w0.y = X2; w0.z = Y1; w0.w = Y2;
      uint4 w1; w1.x = X3; w1.y = X4; w1.z = Y3; w1.w = Y4;
      pf[jj * 2 + 0] = *reinterpret_cast<const v8s*>(&w0);
      pf[jj * 2 + 1] = *reinterpret_cast<const v8s*>(&w1);
    }
  };

  auto pv = [&](const u16* Vb, v8s (&pf)[4]) {
    v8s vf[2][4];
#pragma unroll
    for (int n = 0; n < 2; ++n) {
      const int row = n * 32 + l31;
#pragma unroll
      for (int ks = 0; ks < 4; ++ks)
        vf[n][ks] = *reinterpret_cast<const v8s*>(
            Vb + (size_t)(row * 8 + ((ks * 2 + lh) ^ (row & 7))) * 8);
    }
    __builtin_amdgcn_s_setprio(1);
#pragma unroll
    for (int ks = 0; ks < 4; ++ks) {
      oacc[0] = __builtin_amdgcn_mfma_f32_32x32x16_bf16(pf[ks], vf[0][ks], oacc[0], 0, 0, 0);
      oacc[1] = __builtin_amdgcn_mfma_f32_32x32x16_bf16(pf[ks], vf[1][ks], oacc[1], 0, 0, 0);
    }
    __builtin_amdgcn_s_setprio(0);
  };

  f32x16 sacc0[2], sacc1[2];

  auto body2 = [&](int t, int b0, int b1, int b2, int b3, bool doStage) {
    asm volatile("s_waitcnt vmcnt(0)\n\ts_barrier" ::: "memory");
    if (doStage) { stageKV(b2, t + 2); stageKV(b3, t + 3); }
    qk(&Ks[b0][0], sacc0);
    qk(&Ks[b1][0], sacc1);
    v8s pf0[4], pf1[4];
    pack(sacc0, pf0);
    pack(sacc1, pf1);
    pv(&Vs[b0][0], pf0);
    pv(&Vs[b1][0], pf1);
  };

  stageKV(0, 0);
  stageKV(1, 1);

  for (int tt = 0; tt < 60; tt += 4) {
    body2(tt, 0, 1, 2, 3, true);
    body2(tt + 2, 2, 3, 0, 1, true);
  }
  body2(60, 0, 1, 2, 3, true);
  body2(62, 2, 3, 0, 1, false);

  u32 ua = __float_as_uint(lsum), ub = ua;
  asm("v_permlane32_swap_b32 %0, %1" : "+v"(ua), "+v"(ub));
  const float lf = __uint_as_float(ua) + __uint_as_float(ub);

#pragma unroll
  for (int r = 0; r < 16; ++r) {
    const int crow = (r & 3) + 8 * (r >> 2) + 4 * lh;
    const float inv = __builtin_amdgcn_rcpf(__shfl(lf, crow));
    const int q = q0 + crow;
    const size_t base = (size_t)q * DM + h * HDIM + l31;
    Aout[base] = f2bs(oacc[0][r] * inv);
    Aout[base + 32] = f2bs(oacc[1][r] * inv);
  }
}

// ---- launcher ----------------------------------------------------------
extern "C" void kernel_launch(void* const* d_in, const int* in_sizes, int n_in,
                              void* d_out, int out_size, void* d_ws, size_t ws_size,
                              hipStream_t stream) {
  const float* x  = (const float*)d_in[0];
  const float* wq = (const float*)d_in[1];
  const float* bq = (const float*)d_in[2];
  const float* wk = (const float*)d_in[3];
  const float* bk = (const float*)d_in[4];
  const float* wv = (const float*)d_in[5];
  const float* bv = (const float*)d_in[6];
  const float* wo = (const float*)d_in[7];
  const float* bo = (const float*)d_in[8];
  float* out = (float*)d_out;

  char* ws = (char*)d_ws;
  u16* xb  = (u16*)(ws);                          // [4096][1024] bf16, 8MB
  u16* wqT = (u16*)(ws + (8u << 20));             // [1024][1024] bf16, 2MB each
  u16* wkT = wqT + 1024 * 1024;
  u16* wvT = wkT + 1024 * 1024;
  u16* woT = wvT + 1024 * 1024;
  u16* Qh  = (u16*)(ws + (16u << 20));            // [16][4096][64] bf16, 8MB
  u16* Kh  = Qh + 16 * 4096 * 64;
  u16* Vth = Kh + 16 * 4096 * 64;                 // [16][64][4096]
  u16* Ao  = Vth + 16 * 4096 * 64;                // [4096][1024]

  dim3 pg(16, 16, 5);
  k_prep<<<pg, 256, 0, stream>>>(x, wq, wk, wv, wo, xb, wqT, wkT, wvT, woT);
  dim3 gg(32, 8, 3);
  k_gemm_qkv<<<gg, 256, 0, stream>>>(xb, wqT, wkT, wvT, bq, bk, bv, Qh, Kh, Vth);
  k_attn<<<512, 256, 0, stream>>>(Qh, Kh, Vth, Ao);
  dim3 og(32, 16);
  k_gemm_o<<<og, 256, 0, stream>>>(Ao, woT, bo, out);
}